// Round 2
// baseline (11548.760 us; speedup 1.0000x reference)
//
#include <hip/hip_runtime.h>
#include <hip/hip_bf16.h>
#include <math.h>

#define B_SZ    64
#define SEQ     2048
#define DMODEL  128
#define DINNER  256
#define DSTATE  16
#define NLAYERS 5

typedef unsigned short u16;
typedef __attribute__((ext_vector_type(8))) short bf16x8;
typedef __attribute__((ext_vector_type(4))) float f32x4;

static __device__ __forceinline__ float bf2f(u16 u){
  union { unsigned u; float f; } a; a.u = ((unsigned)u) << 16; return a.f;
}
static __device__ __forceinline__ u16 f2bf(float f){
  union { float f; unsigned u; } a; a.f = f;
  unsigned r = a.u + 0x7fffu + ((a.u >> 16) & 1u);
  return (u16)(r >> 16);
}
static __device__ __forceinline__ float sigm(float x){ return 1.f/(1.f+__expf(-x)); }
static __device__ __forceinline__ float siluf(float x){ return x/(1.f+__expf(-x)); }

#define MFMA16(a,b,c) __builtin_amdgcn_mfma_f32_16x16x32_bf16((a),(b),(c),0,0,0)

/* ---------------- weight prep: transpose to [N][K] + bf16 ---------------- */
__global__ __launch_bounds__(256) void prep_kernel(
    const float* __restrict__ in_w, const float* __restrict__ xp_w,
    const float* __restrict__ dt_w, const float* __restrict__ out_w,
    u16* __restrict__ WT1, u16* __restrict__ WT2, u16* __restrict__ WT3){
  int idx = blockIdx.x*256 + threadIdx.x;
  const int n1 = NLAYERS*512*128, n2 = NLAYERS*288*256, n3 = NLAYERS*128*256;
  if (idx < n1){
    int l = idx/(512*128), r = idx%(512*128), n = r/128, k = r%128;
    WT1[idx] = f2bf(in_w[((size_t)l*128 + k)*512 + n]);
  } else if (idx < n1+n2){
    int t = idx-n1; int l=t/(288*256), r=t%(288*256), n=r/256, k=r%256;
    float v = (n<32) ? xp_w[((size_t)l*256+k)*32 + n]
                     : dt_w[((size_t)l*256+k)*256 + (n-32)];
    WT2[t] = f2bf(v);
  } else if (idx < n1+n2+n3){
    int t = idx-n1-n2; int l=t/(128*256), r=t%(128*256), n=r/256, k=r%256;
    WT3[t] = f2bf(out_w[((size_t)l*256+k)*128 + n]);
  }
}

/* ---------------- embedding: h = x @ emb_w + emb_b (f32) ---------------- */
__global__ __launch_bounds__(256) void emb_kernel(
    const float* __restrict__ x, const float* __restrict__ ew,
    const float* __restrict__ eb, float* __restrict__ H){
  int idx = blockIdx.x*256 + threadIdx.x;
  int m = idx >> 7, d = idx & 127;
  float s = eb[d];
  #pragma unroll
  for (int k=0;k<16;++k) s += x[(size_t)m*16+k]*ew[k*128+d];
  H[(size_t)m*128+d] = s;
}

/* ------- GEMM1: xz = h @ in_w + b ; u=silu(xz[:256]) zs=silu(xz[256:]) --- */
__global__ __launch_bounds__(256) void gemm1_kernel(
    const float* __restrict__ H, const u16* __restrict__ WT,
    const float* __restrict__ bias, u16* __restrict__ U, u16* __restrict__ ZS){
  const int lane = threadIdx.x & 63, wave = threadIdx.x >> 6;
  const int m0 = blockIdx.x*64 + wave*16;
  const int lr = lane & 15, kg = lane >> 4;
  bf16x8 a[4];
  const float* arow = H + (size_t)(m0+lr)*128 + kg*8;
  #pragma unroll
  for (int f=0; f<4; ++f){
    float4 x0 = *(const float4*)(arow + f*32);
    float4 x1 = *(const float4*)(arow + f*32 + 4);
    bf16x8 t;
    t[0]=(short)f2bf(x0.x); t[1]=(short)f2bf(x0.y); t[2]=(short)f2bf(x0.z); t[3]=(short)f2bf(x0.w);
    t[4]=(short)f2bf(x1.x); t[5]=(short)f2bf(x1.y); t[6]=(short)f2bf(x1.z); t[7]=(short)f2bf(x1.w);
    a[f]=t;
  }
  for (int n0=0; n0<512; n0+=16){
    const u16* wrow = WT + (size_t)(n0+lr)*128 + kg*8;
    f32x4 acc = {0.f,0.f,0.f,0.f};
    #pragma unroll
    for (int f=0; f<4; ++f){
      bf16x8 bv = *(const bf16x8*)(wrow + f*32);
      acc = MFMA16(a[f], bv, acc);
    }
    int col = n0 + lr;
    float bs = bias[col];
    u16* dst; int cc;
    if (col < 256){ dst = U; cc = col; } else { dst = ZS; cc = col-256; }
    #pragma unroll
    for (int j=0;j<4;++j){
      float v = acc[j] + bs;
      dst[(size_t)(m0 + kg*4 + j)*256 + cc] = f2bf(siluf(v));
    }
  }
}

/* -- GEMM2: x_dbl = u @ xp_w (N 0..31, f32), dt = softplus(u @ dt_w) bf16 -- */
__global__ __launch_bounds__(256) void gemm2_kernel(
    const u16* __restrict__ Uin, const u16* __restrict__ WT,
    const float* __restrict__ xpb, const float* __restrict__ dtb,
    float* __restrict__ BC, u16* __restrict__ DT){
  const int lane = threadIdx.x & 63, wave = threadIdx.x >> 6;
  const int m0 = blockIdx.x*64 + wave*16;
  const int lr = lane & 15, kg = lane >> 4;
  bf16x8 a[8];
  const u16* arow = Uin + (size_t)(m0+lr)*256 + kg*8;
  #pragma unroll
  for (int f=0; f<8; ++f) a[f] = *(const bf16x8*)(arow + f*32);
  for (int n0=0; n0<288; n0+=16){
    const u16* wrow = WT + (size_t)(n0+lr)*256 + kg*8;
    f32x4 acc = {0.f,0.f,0.f,0.f};
    #pragma unroll
    for (int f=0; f<8; ++f){
      bf16x8 bv = *(const bf16x8*)(wrow + f*32);
      acc = MFMA16(a[f], bv, acc);
    }
    int col = n0 + lr;
    if (col < 32){
      float bs = xpb[col];
      #pragma unroll
      for (int j=0;j<4;++j)
        BC[(size_t)(m0+kg*4+j)*32 + col] = acc[j] + bs;
    } else {
      float bs = dtb[col-32];
      #pragma unroll
      for (int j=0;j<4;++j){
        float v = acc[j] + bs;
        float sp = fmaxf(v,0.f) + __logf(1.f + __expf(-fabsf(v)));
        DT[(size_t)(m0+kg*4+j)*256 + (col-32)] = f2bf(sp);
      }
    }
  }
}

/* -------- scan: h_t = h*exp(dt*A) + (dt*u)B ; y=sum(h*C)+D*u ; ys=y*zs --- */
__global__ __launch_bounds__(64) void scan_kernel(
    u16* UY, const u16* __restrict__ DT, const float* __restrict__ BC,
    const u16* __restrict__ ZS, const float* __restrict__ Alog,
    const float* __restrict__ Dp){
  const int b = blockIdx.x >> 2;                 /* chunk-local batch */
  const int c = ((blockIdx.x & 3) << 6) + threadIdx.x;
  float a2[16]; bool geo = true;
  #pragma unroll
  for (int i=0;i<16;++i){
    float A = -__expf(Alog[c*16+i]);
    a2[i] = A * 1.44269504f;
    if (fabsf(A + (float)(i+1)) > 1e-3f) geo = false;
  }
  const float Dv = Dp[c];
  float h[16];
  #pragma unroll
  for (int i=0;i<16;++i) h[i]=0.f;
  const size_t mbase = (size_t)b*SEQ;
  if (geo){
    for (int t=0;t<SEQ;++t){
      const size_t m = mbase + t;
      float u  = bf2f(UY[m*256+c]);
      float dt = bf2f(DT[m*256+c]);
      float zs = bf2f(ZS[m*256+c]);
      float Bv[16], Cv[16];
      const float4* bc4 = (const float4*)(BC + m*32);
      #pragma unroll
      for (int q=0;q<4;++q){ float4 tt=bc4[q];   Bv[q*4]=tt.x; Bv[q*4+1]=tt.y; Bv[q*4+2]=tt.z; Bv[q*4+3]=tt.w; }
      #pragma unroll
      for (int q=0;q<4;++q){ float4 tt=bc4[4+q]; Cv[q*4]=tt.x; Cv[q*4+1]=tt.y; Cv[q*4+2]=tt.z; Cv[q*4+3]=tt.w; }
      float du = dt*u;
      float r = exp2f(-1.44269504f*dt);
      float p = 1.f, s0=0.f, s1=0.f, s2=0.f, s3=0.f;
      #pragma unroll
      for (int i=0;i<16;i+=4){
        p *= r; h[i]   = h[i]  *p + du*Bv[i];   s0 += h[i]  *Cv[i];
        p *= r; h[i+1] = h[i+1]*p + du*Bv[i+1]; s1 += h[i+1]*Cv[i+1];
        p *= r; h[i+2] = h[i+2]*p + du*Bv[i+2]; s2 += h[i+2]*Cv[i+2];
        p *= r; h[i+3] = h[i+3]*p + du*Bv[i+3]; s3 += h[i+3]*Cv[i+3];
      }
      float y = (s0+s1)+(s2+s3) + Dv*u;
      UY[m*256+c] = f2bf(y*zs);
    }
  } else {
    for (int t=0;t<SEQ;++t){
      const size_t m = mbase + t;
      float u  = bf2f(UY[m*256+c]);
      float dt = bf2f(DT[m*256+c]);
      float zs = bf2f(ZS[m*256+c]);
      float Bv[16], Cv[16];
      const float4* bc4 = (const float4*)(BC + m*32);
      #pragma unroll
      for (int q=0;q<4;++q){ float4 tt=bc4[q];   Bv[q*4]=tt.x; Bv[q*4+1]=tt.y; Bv[q*4+2]=tt.z; Bv[q*4+3]=tt.w; }
      #pragma unroll
      for (int q=0;q<4;++q){ float4 tt=bc4[4+q]; Cv[q*4]=tt.x; Cv[q*4+1]=tt.y; Cv[q*4+2]=tt.z; Cv[q*4+3]=tt.w; }
      float du = dt*u;
      float s0=0.f, s1=0.f, s2=0.f, s3=0.f;
      #pragma unroll
      for (int i=0;i<16;i+=4){
        float d0 = exp2f(dt*a2[i]);   h[i]   = h[i]  *d0 + du*Bv[i];   s0 += h[i]  *Cv[i];
        float d1 = exp2f(dt*a2[i+1]); h[i+1] = h[i+1]*d1 + du*Bv[i+1]; s1 += h[i+1]*Cv[i+1];
        float d2 = exp2f(dt*a2[i+2]); h[i+2] = h[i+2]*d2 + du*Bv[i+2]; s2 += h[i+2]*Cv[i+2];
        float d3 = exp2f(dt*a2[i+3]); h[i+3] = h[i+3]*d3 + du*Bv[i+3]; s3 += h[i+3]*Cv[i+3];
      }
      float y = (s0+s1)+(s2+s3) + Dv*u;
      UY[m*256+c] = f2bf(y*zs);
    }
  }
}

/* --- GEMM3 (in place): H = ys @ out_w + out_b + H  (H is the residual) --- */
__global__ __launch_bounds__(256) void gemm3_kernel(
    const u16* __restrict__ YS, const u16* __restrict__ WT,
    const float* __restrict__ ob, float* __restrict__ H){
  const int lane = threadIdx.x & 63, wave = threadIdx.x >> 6;
  const int m0 = blockIdx.x*64 + wave*16;
  const int lr = lane & 15, kg = lane >> 4;
  bf16x8 a[8];
  const u16* arow = YS + (size_t)(m0+lr)*256 + kg*8;
  #pragma unroll
  for (int f=0; f<8; ++f) a[f] = *(const bf16x8*)(arow + f*32);
  for (int n0=0; n0<128; n0+=16){
    const u16* wrow = WT + (size_t)(n0+lr)*256 + kg*8;
    f32x4 acc = {0.f,0.f,0.f,0.f};
    #pragma unroll
    for (int f=0; f<8; ++f){
      bf16x8 bv = *(const bf16x8*)(wrow + f*32);
      acc = MFMA16(a[f], bv, acc);
    }
    int col = n0 + lr;
    float bs = ob[col];
    #pragma unroll
    for (int j=0;j<4;++j){
      size_t r = (size_t)(m0 + kg*4 + j);
      H[r*128 + col] = acc[j] + bs + H[r*128 + col];   /* same element: safe */
    }
  }
}

/* ---------------- layernorm, in place, one wave per row ------------------ */
__global__ __launch_bounds__(256) void ln_kernel(
    float* __restrict__ H, const float* __restrict__ g, const float* __restrict__ bb){
  const int wave = threadIdx.x >> 6, lane = threadIdx.x & 63;
  const size_t row = (size_t)blockIdx.x*4 + wave;
  float* p = H + row*128;
  float2 v = *(float2*)(p + lane*2);
  float s = v.x + v.y, q = v.x*v.x + v.y*v.y;
  #pragma unroll
  for (int o=1;o<64;o<<=1){ s += __shfl_xor(s,o); q += __shfl_xor(q,o); }
  float mu  = s*0.0078125f;
  float var = q*0.0078125f - mu*mu;
  float inv = rsqrtf(var + 1e-5f);
  float g0=g[lane*2], g1=g[lane*2+1], b0=bb[lane*2], b1=bb[lane*2+1];
  v.x = (v.x-mu)*inv*g0 + b0;
  v.y = (v.y-mu)*inv*g1 + b1;
  *(float2*)(p + lane*2) = v;
}

/* ---------------- mean over SEQ (PO pre-offset by chunk) ---------------- */
__global__ __launch_bounds__(128) void pool_kernel(
    const float* __restrict__ H, float* __restrict__ P){
  const int b = blockIdx.x, d = threadIdx.x;
  float s = 0.f;
  for (int t=0;t<SEQ;++t) s += H[((size_t)b*SEQ+t)*128 + d];
  P[b*128 + d] = s * (1.f/SEQ);
}

/* ---------------- head MLP + final formula ---------------- */
__global__ __launch_bounds__(64) void head_kernel(
    const float* __restrict__ P, const float* __restrict__ o1w,
    const float* __restrict__ o1b, const float* __restrict__ o2w,
    const float* __restrict__ o2b, const float* __restrict__ origins,
    float* __restrict__ out){
  const int b = threadIdx.x;
  if (b >= B_SZ) return;
  float hid[64];
  for (int j=0;j<64;++j){
    float s = o1b[j];
    for (int d=0;d<128;++d) s += P[b*128+d]*o1w[d*64+j];
    hid[j] = fmaxf(s, 0.f);
  }
  float pr[3];
  for (int q=0;q<3;++q){
    float s = o2b[q];
    for (int j=0;j<64;++j) s += hid[j]*o2w[j*3+q];
    pr[q] = 2.f*sigm(s);
  }
  const float* l1 = origins + ((size_t)b*SEQ + (SEQ-1))*16;
  const float* l2 = origins + ((size_t)b*SEQ + (SEQ-2))*16;
  float price=l1[0], ry_n=l1[1], ry_b=l2[1], gy_n=l1[2], gy_b=l2[2], ny_n=l1[3], ny_b=l2[3];
  out[b] = price*pr[0]*ry_n/ry_b*2.f*(pr[1]*sigm(gy_n-gy_b) + pr[2]*sigm(ny_n-ny_b));
}

extern "C" void kernel_launch(void* const* d_in, const int* in_sizes, int n_in,
                              void* d_out, int out_size, void* d_ws, size_t ws_size,
                              hipStream_t stream){
  const float* origins = (const float*)d_in[0];
  const float* x      = (const float*)d_in[1];
  const float* emb_w  = (const float*)d_in[2];
  const float* emb_b  = (const float*)d_in[3];
  const float* in_w   = (const float*)d_in[4];
  const float* in_b   = (const float*)d_in[5];
  const float* xp_w   = (const float*)d_in[6];
  const float* xp_b   = (const float*)d_in[7];
  const float* dt_w   = (const float*)d_in[8];
  const float* dt_b   = (const float*)d_in[9];
  const float* out_w  = (const float*)d_in[10];
  const float* out_b  = (const float*)d_in[11];
  const float* A_log  = (const float*)d_in[12];
  const float* Dp     = (const float*)d_in[13];
  const float* ln_g   = (const float*)d_in[14];
  const float* ln_b   = (const float*)d_in[15];
  const float* o1_w   = (const float*)d_in[16];
  const float* o1_b   = (const float*)d_in[17];
  const float* o2_w   = (const float*)d_in[18];
  const float* o2_b   = (const float*)d_in[19];
  float* outp = (float*)d_out;

  auto al = [](size_t b)->size_t{ return (b + 255) & ~(size_t)255; };
  const size_t wt1_b = al((size_t)NLAYERS*512*128*2);
  const size_t wt2_b = al((size_t)NLAYERS*288*256*2);
  const size_t wt3_b = al((size_t)NLAYERS*128*256*2);
  const size_t po_b  = al((size_t)B_SZ*128*4);
  const size_t fixed = wt1_b + wt2_b + wt3_b + po_b;

  /* pick largest batch-chunk CB whose footprint fits ws_size */
  int CB = 0;
  static const int cand[7] = {64,32,16,8,4,2,1};
  size_t h_b=0, u_b=0, bc_b=0;
  for (int i=0;i<7;++i){
    int cb = cand[i];
    size_t hh = al((size_t)cb*SEQ*128*4);
    size_t uu = al((size_t)cb*SEQ*256*2);
    size_t bb = al((size_t)cb*SEQ*32*4);
    if (fixed + hh + 3*uu + bb <= ws_size){ CB=cb; h_b=hh; u_b=uu; bc_b=bb; break; }
  }
  if (!CB) return;

  char* ws = (char*)d_ws;
  size_t off = 0;
  auto take = [&](size_t bytes)->char*{ char* p = ws + off; off += bytes; return p; };
  u16*   WT1 = (u16*)take(wt1_b);
  u16*   WT2 = (u16*)take(wt2_b);
  u16*   WT3 = (u16*)take(wt3_b);
  float* PO  = (float*)take(po_b);
  float* H   = (float*)take(h_b);
  u16*   U   = (u16*)take(u_b);    /* also holds ys after scan */
  u16*   ZS  = (u16*)take(u_b);
  u16*   DT  = (u16*)take(u_b);
  float* BC  = (float*)take(bc_b);

  prep_kernel<<<3360, 256, 0, stream>>>(in_w, xp_w, dt_w, out_w, WT1, WT2, WT3);

  const int NC = B_SZ / CB;
  const int Mc = CB * SEQ;
  for (int ci=0; ci<NC; ++ci){
    const int b0 = ci * CB;
    const size_t R0 = (size_t)b0 * SEQ;
    emb_kernel<<<(Mc*DMODEL)/256, 256, 0, stream>>>(x + R0*16, emb_w, emb_b, H);
    for (int l=0;l<NLAYERS;++l){
      gemm1_kernel<<<Mc/64, 256, 0, stream>>>(H, WT1 + (size_t)l*512*128,
                                              in_b + l*512, U, ZS);
      gemm2_kernel<<<Mc/64, 256, 0, stream>>>(U, WT2 + (size_t)l*288*256,
                                              xp_b + l*32, dt_b + l*256, BC, DT);
      scan_kernel<<<CB*4, 64, 0, stream>>>(U, DT, BC, ZS,
                                           A_log + (size_t)l*DINNER*DSTATE, Dp + l*DINNER);
      gemm3_kernel<<<Mc/64, 256, 0, stream>>>(U, WT3 + (size_t)l*128*256,
                                              out_b + l*128, H);
      ln_kernel<<<Mc/4, 256, 0, stream>>>(H, ln_g + l*128, ln_b + l*128);
    }
    pool_kernel<<<CB, 128, 0, stream>>>(H, PO + (size_t)b0*128);
  }
  head_kernel<<<1, 64, 0, stream>>>(PO, o1_w, o1_b, o2_w, o2_b, origins, outp);
}

// Round 3
// 3361.835 us; speedup vs baseline: 3.4353x; 3.4353x over previous
//
#include <hip/hip_runtime.h>
#include <hip/hip_bf16.h>
#include <math.h>

#define B_SZ    64
#define SEQ     2048
#define DMODEL  128
#define DINNER  256
#define DSTATE  16
#define NLAYERS 5

typedef unsigned short u16;
typedef __attribute__((ext_vector_type(8))) short bf16x8;
typedef __attribute__((ext_vector_type(4))) float f32x4;

static __device__ __forceinline__ float bf2f(u16 u){
  union { unsigned u; float f; } a; a.u = ((unsigned)u) << 16; return a.f;
}
static __device__ __forceinline__ u16 f2bf(float f){
  union { float f; unsigned u; } a; a.f = f;
  unsigned r = a.u + 0x7fffu + ((a.u >> 16) & 1u);
  return (u16)(r >> 16);
}
static __device__ __forceinline__ float sigm(float x){ return 1.f/(1.f+__expf(-x)); }
static __device__ __forceinline__ float siluf(float x){ return x/(1.f+__expf(-x)); }

#define MFMA16(a,b,c) __builtin_amdgcn_mfma_f32_16x16x32_bf16((a),(b),(c),0,0,0)

/* ---------------- weight prep: transpose to [N][K] + bf16 ---------------- */
__global__ __launch_bounds__(256) void prep_kernel(
    const float* __restrict__ in_w, const float* __restrict__ xp_w,
    const float* __restrict__ dt_w, const float* __restrict__ out_w,
    u16* __restrict__ WT1, u16* __restrict__ WT2, u16* __restrict__ WT3){
  int idx = blockIdx.x*256 + threadIdx.x;
  const int n1 = NLAYERS*512*128, n2 = NLAYERS*288*256, n3 = NLAYERS*128*256;
  if (idx < n1){
    int l = idx/(512*128), r = idx%(512*128), n = r/128, k = r%128;
    WT1[idx] = f2bf(in_w[((size_t)l*128 + k)*512 + n]);
  } else if (idx < n1+n2){
    int t = idx-n1; int l=t/(288*256), r=t%(288*256), n=r/256, k=r%256;
    float v = (n<32) ? xp_w[((size_t)l*256+k)*32 + n]
                     : dt_w[((size_t)l*256+k)*256 + (n-32)];
    WT2[t] = f2bf(v);
  } else if (idx < n1+n2+n3){
    int t = idx-n1-n2; int l=t/(128*256), r=t%(128*256), n=r/256, k=r%256;
    WT3[t] = f2bf(out_w[((size_t)l*256+k)*128 + n]);
  }
}

/* ---------------- embedding: h = x @ emb_w + emb_b (f32) ---------------- */
__global__ __launch_bounds__(256) void emb_kernel(
    const float* __restrict__ x, const float* __restrict__ ew,
    const float* __restrict__ eb, float* __restrict__ H){
  int idx = blockIdx.x*256 + threadIdx.x;
  int m = idx >> 7, d = idx & 127;
  float s = eb[d];
  #pragma unroll
  for (int k=0;k<16;++k) s += x[(size_t)m*16+k]*ew[k*128+d];
  H[(size_t)m*128+d] = s;
}

/* ------- GEMM1: xz = h @ in_w + b ; u=silu(xz[:256]) zs=silu(xz[256:]) --- */
__global__ __launch_bounds__(256) void gemm1_kernel(
    const float* __restrict__ H, const u16* __restrict__ WT,
    const float* __restrict__ bias, u16* __restrict__ U, u16* __restrict__ ZS){
  const int lane = threadIdx.x & 63, wave = threadIdx.x >> 6;
  const int m0 = blockIdx.x*64 + wave*16;
  const int lr = lane & 15, kg = lane >> 4;
  bf16x8 a[4];
  const float* arow = H + (size_t)(m0+lr)*128 + kg*8;
  #pragma unroll
  for (int f=0; f<4; ++f){
    float4 x0 = *(const float4*)(arow + f*32);
    float4 x1 = *(const float4*)(arow + f*32 + 4);
    bf16x8 t;
    t[0]=(short)f2bf(x0.x); t[1]=(short)f2bf(x0.y); t[2]=(short)f2bf(x0.z); t[3]=(short)f2bf(x0.w);
    t[4]=(short)f2bf(x1.x); t[5]=(short)f2bf(x1.y); t[6]=(short)f2bf(x1.z); t[7]=(short)f2bf(x1.w);
    a[f]=t;
  }
  for (int n0=0; n0<512; n0+=16){
    const u16* wrow = WT + (size_t)(n0+lr)*128 + kg*8;
    f32x4 acc = {0.f,0.f,0.f,0.f};
    #pragma unroll
    for (int f=0; f<4; ++f){
      bf16x8 bv = *(const bf16x8*)(wrow + f*32);
      acc = MFMA16(a[f], bv, acc);
    }
    int col = n0 + lr;
    float bs = bias[col];
    u16* dst; int cc;
    if (col < 256){ dst = U; cc = col; } else { dst = ZS; cc = col-256; }
    #pragma unroll
    for (int j=0;j<4;++j){
      float v = acc[j] + bs;
      dst[(size_t)(m0 + kg*4 + j)*256 + cc] = f2bf(siluf(v));
    }
  }
}

/* -- GEMM2: x_dbl = u @ xp_w (N 0..31, f32), dt = softplus(u @ dt_w) bf16 -- */
__global__ __launch_bounds__(256) void gemm2_kernel(
    const u16* __restrict__ Uin, const u16* __restrict__ WT,
    const float* __restrict__ xpb, const float* __restrict__ dtb,
    float* __restrict__ BC, u16* __restrict__ DT){
  const int lane = threadIdx.x & 63, wave = threadIdx.x >> 6;
  const int m0 = blockIdx.x*64 + wave*16;
  const int lr = lane & 15, kg = lane >> 4;
  bf16x8 a[8];
  const u16* arow = Uin + (size_t)(m0+lr)*256 + kg*8;
  #pragma unroll
  for (int f=0; f<8; ++f) a[f] = *(const bf16x8*)(arow + f*32);
  for (int n0=0; n0<288; n0+=16){
    const u16* wrow = WT + (size_t)(n0+lr)*256 + kg*8;
    f32x4 acc = {0.f,0.f,0.f,0.f};
    #pragma unroll
    for (int f=0; f<8; ++f){
      bf16x8 bv = *(const bf16x8*)(wrow + f*32);
      acc = MFMA16(a[f], bv, acc);
    }
    int col = n0 + lr;
    if (col < 32){
      float bs = xpb[col];
      #pragma unroll
      for (int j=0;j<4;++j)
        BC[(size_t)(m0+kg*4+j)*32 + col] = acc[j] + bs;
    } else {
      float bs = dtb[col-32];
      #pragma unroll
      for (int j=0;j<4;++j){
        float v = acc[j] + bs;
        float sp = fmaxf(v,0.f) + __logf(1.f + __expf(-fabsf(v)));
        DT[(size_t)(m0+kg*4+j)*256 + (col-32)] = f2bf(sp);
      }
    }
  }
}

/* ====================== segmented scan (3 passes) ======================== */
/* pass 1: per (b, cgroup, seg): local scan from h=0 over L steps.
   Writes per-state decay product P and local end-state h to SGP/SGH.      */
__global__ __launch_bounds__(64) void scan_p1(
    const u16* __restrict__ U, const u16* __restrict__ DT,
    const float* __restrict__ BC, const float* __restrict__ Alog,
    float* __restrict__ SGP, float* __restrict__ SGH, int nseg, int L){
  const int seg = blockIdx.x % nseg;
  const int rem = blockIdx.x / nseg;
  const int cg = rem & 3, b = rem >> 2;
  const int c = (cg<<6) + threadIdx.x;
  float a2[16]; bool geo = true;
  #pragma unroll
  for (int i=0;i<16;++i){
    float A = -__expf(Alog[c*16+i]);
    a2[i] = A * 1.44269504f;
    if (fabsf(A + (float)(i+1)) > 1e-3f) geo = false;
  }
  float h[16], P[16];
  #pragma unroll
  for (int i=0;i<16;++i){ h[i]=0.f; P[i]=1.f; }
  const size_t mbase = (size_t)b*SEQ + (size_t)seg*L;
  if (geo){
    for (int t=0;t<L;++t){
      const size_t m = mbase + t;
      float u  = bf2f(U[m*256+c]);
      float dt = bf2f(DT[m*256+c]);
      float Bv[16];
      const float4* bc4 = (const float4*)(BC + m*32);
      #pragma unroll
      for (int q=0;q<4;++q){ float4 tt=bc4[q]; Bv[q*4]=tt.x; Bv[q*4+1]=tt.y; Bv[q*4+2]=tt.z; Bv[q*4+3]=tt.w; }
      float du = dt*u;
      float r = exp2f(-1.44269504f*dt);
      float p = 1.f;
      #pragma unroll
      for (int i=0;i<16;++i){
        p *= r;
        h[i] = h[i]*p + du*Bv[i];
        P[i] *= p;
      }
    }
  } else {
    for (int t=0;t<L;++t){
      const size_t m = mbase + t;
      float u  = bf2f(U[m*256+c]);
      float dt = bf2f(DT[m*256+c]);
      float Bv[16];
      const float4* bc4 = (const float4*)(BC + m*32);
      #pragma unroll
      for (int q=0;q<4;++q){ float4 tt=bc4[q]; Bv[q*4]=tt.x; Bv[q*4+1]=tt.y; Bv[q*4+2]=tt.z; Bv[q*4+3]=tt.w; }
      float du = dt*u;
      #pragma unroll
      for (int i=0;i<16;++i){
        float d0 = exp2f(dt*a2[i]);
        h[i] = h[i]*d0 + du*Bv[i];
        P[i] *= d0;
      }
    }
  }
  #pragma unroll
  for (int i=0;i<16;++i){
    size_t k = (((size_t)b*nseg+seg)*16+i)*256 + c;
    SGP[k] = P[i];
    SGH[k] = h[i];
  }
}

/* pass 2: sequential combine over segments; overwrites SGP with h0(seg). */
__global__ __launch_bounds__(256) void scan_p2(
    float* __restrict__ SGP, const float* __restrict__ SGH, int nseg){
  const int idx = blockIdx.x*256 + threadIdx.x;   /* (b,i,c) with c fastest */
  const int c = idx & 255, i = (idx>>8)&15, b = idx>>12;
  float h = 0.f;
  for (int s=0;s<nseg;++s){
    size_t k = (((size_t)b*nseg+s)*16+i)*256 + c;
    float Pv = SGP[k], hl = SGH[k];
    SGP[k] = h;                 /* h0 entering segment s */
    h = Pv*h + hl;
  }
}

/* pass 3: re-scan each segment from its h0, emit y*silu(z) in place of U. */
__global__ __launch_bounds__(64) void scan_p3(
    u16* __restrict__ UY, const u16* __restrict__ DT, const float* __restrict__ BC,
    const u16* __restrict__ ZS, const float* __restrict__ Alog,
    const float* __restrict__ Dp, const float* __restrict__ SGP, int nseg, int L){
  const int seg = blockIdx.x % nseg;
  const int rem = blockIdx.x / nseg;
  const int cg = rem & 3, b = rem >> 2;
  const int c = (cg<<6) + threadIdx.x;
  float a2[16]; bool geo = true;
  #pragma unroll
  for (int i=0;i<16;++i){
    float A = -__expf(Alog[c*16+i]);
    a2[i] = A * 1.44269504f;
    if (fabsf(A + (float)(i+1)) > 1e-3f) geo = false;
  }
  const float Dv = Dp[c];
  float h[16];
  #pragma unroll
  for (int i=0;i<16;++i)
    h[i] = SGP[(((size_t)b*nseg+seg)*16+i)*256 + c];
  const size_t mbase = (size_t)b*SEQ + (size_t)seg*L;
  if (geo){
    for (int t=0;t<L;++t){
      const size_t m = mbase + t;
      float u  = bf2f(UY[m*256+c]);
      float dt = bf2f(DT[m*256+c]);
      float zs = bf2f(ZS[m*256+c]);
      float Bv[16], Cv[16];
      const float4* bc4 = (const float4*)(BC + m*32);
      #pragma unroll
      for (int q=0;q<4;++q){ float4 tt=bc4[q];   Bv[q*4]=tt.x; Bv[q*4+1]=tt.y; Bv[q*4+2]=tt.z; Bv[q*4+3]=tt.w; }
      #pragma unroll
      for (int q=0;q<4;++q){ float4 tt=bc4[4+q]; Cv[q*4]=tt.x; Cv[q*4+1]=tt.y; Cv[q*4+2]=tt.z; Cv[q*4+3]=tt.w; }
      float du = dt*u;
      float r = exp2f(-1.44269504f*dt);
      float p = 1.f, s0=0.f, s1=0.f, s2=0.f, s3=0.f;
      #pragma unroll
      for (int i=0;i<16;i+=4){
        p *= r; h[i]   = h[i]  *p + du*Bv[i];   s0 += h[i]  *Cv[i];
        p *= r; h[i+1] = h[i+1]*p + du*Bv[i+1]; s1 += h[i+1]*Cv[i+1];
        p *= r; h[i+2] = h[i+2]*p + du*Bv[i+2]; s2 += h[i+2]*Cv[i+2];
        p *= r; h[i+3] = h[i+3]*p + du*Bv[i+3]; s3 += h[i+3]*Cv[i+3];
      }
      float y = (s0+s1)+(s2+s3) + Dv*u;
      UY[m*256+c] = f2bf(y*zs);
    }
  } else {
    for (int t=0;t<L;++t){
      const size_t m = mbase + t;
      float u  = bf2f(UY[m*256+c]);
      float dt = bf2f(DT[m*256+c]);
      float zs = bf2f(ZS[m*256+c]);
      float Bv[16], Cv[16];
      const float4* bc4 = (const float4*)(BC + m*32);
      #pragma unroll
      for (int q=0;q<4;++q){ float4 tt=bc4[q];   Bv[q*4]=tt.x; Bv[q*4+1]=tt.y; Bv[q*4+2]=tt.z; Bv[q*4+3]=tt.w; }
      #pragma unroll
      for (int q=0;q<4;++q){ float4 tt=bc4[4+q]; Cv[q*4]=tt.x; Cv[q*4+1]=tt.y; Cv[q*4+2]=tt.z; Cv[q*4+3]=tt.w; }
      float du = dt*u;
      float s0=0.f, s1=0.f, s2=0.f, s3=0.f;
      #pragma unroll
      for (int i=0;i<16;i+=4){
        float d0 = exp2f(dt*a2[i]);   h[i]   = h[i]  *d0 + du*Bv[i];   s0 += h[i]  *Cv[i];
        float d1 = exp2f(dt*a2[i+1]); h[i+1] = h[i+1]*d1 + du*Bv[i+1]; s1 += h[i+1]*Cv[i+1];
        float d2 = exp2f(dt*a2[i+2]); h[i+2] = h[i+2]*d2 + du*Bv[i+2]; s2 += h[i+2]*Cv[i+2];
        float d3 = exp2f(dt*a2[i+3]); h[i+3] = h[i+3]*d3 + du*Bv[i+3]; s3 += h[i+3]*Cv[i+3];
      }
      float y = (s0+s1)+(s2+s3) + Dv*u;
      UY[m*256+c] = f2bf(y*zs);
    }
  }
}

/* ------------- monolithic scan fallback (if scratch doesn't fit) --------- */
__global__ __launch_bounds__(64) void scan_kernel(
    u16* UY, const u16* __restrict__ DT, const float* __restrict__ BC,
    const u16* __restrict__ ZS, const float* __restrict__ Alog,
    const float* __restrict__ Dp){
  const int b = blockIdx.x >> 2;
  const int c = ((blockIdx.x & 3) << 6) + threadIdx.x;
  float a2[16]; bool geo = true;
  #pragma unroll
  for (int i=0;i<16;++i){
    float A = -__expf(Alog[c*16+i]);
    a2[i] = A * 1.44269504f;
    if (fabsf(A + (float)(i+1)) > 1e-3f) geo = false;
  }
  const float Dv = Dp[c];
  float h[16];
  #pragma unroll
  for (int i=0;i<16;++i) h[i]=0.f;
  const size_t mbase = (size_t)b*SEQ;
  for (int t=0;t<SEQ;++t){
    const size_t m = mbase + t;
    float u  = bf2f(UY[m*256+c]);
    float dt = bf2f(DT[m*256+c]);
    float zs = bf2f(ZS[m*256+c]);
    float Bv[16], Cv[16];
    const float4* bc4 = (const float4*)(BC + m*32);
    #pragma unroll
    for (int q=0;q<4;++q){ float4 tt=bc4[q];   Bv[q*4]=tt.x; Bv[q*4+1]=tt.y; Bv[q*4+2]=tt.z; Bv[q*4+3]=tt.w; }
    #pragma unroll
    for (int q=0;q<4;++q){ float4 tt=bc4[4+q]; Cv[q*4]=tt.x; Cv[q*4+1]=tt.y; Cv[q*4+2]=tt.z; Cv[q*4+3]=tt.w; }
    float du = dt*u;
    float s0=0.f, s1=0.f, s2=0.f, s3=0.f;
    if (geo){
      float r = exp2f(-1.44269504f*dt);
      float p = 1.f;
      #pragma unroll
      for (int i=0;i<16;++i){
        p *= r; h[i] = h[i]*p + du*Bv[i]; s0 += h[i]*Cv[i];
      }
    } else {
      #pragma unroll
      for (int i=0;i<16;++i){
        float d0 = exp2f(dt*a2[i]); h[i] = h[i]*d0 + du*Bv[i]; s0 += h[i]*Cv[i];
      }
    }
    float y = s0+s1+s2+s3 + Dv*u;
    UY[m*256+c] = f2bf(y*zs);
  }
}

/* --- GEMM3 + residual + LayerNorm fused (in place on H) ----------------- */
__global__ __launch_bounds__(256) void gemm3ln_kernel(
    const u16* __restrict__ YS, const u16* __restrict__ WT,
    const float* __restrict__ ob, const float* __restrict__ g,
    const float* __restrict__ bb, float* __restrict__ H){
  const int lane = threadIdx.x & 63, wave = threadIdx.x >> 6;
  const int m0 = blockIdx.x*64 + wave*16;
  const int lr = lane & 15, kg = lane >> 4;
  bf16x8 a[8];
  const u16* arow = YS + (size_t)(m0+lr)*256 + kg*8;
  #pragma unroll
  for (int f=0; f<8; ++f) a[f] = *(const bf16x8*)(arow + f*32);
  float xv[8][4];
  #pragma unroll
  for (int n=0; n<8; ++n){
    const u16* wrow = WT + (size_t)(n*16+lr)*256 + kg*8;
    f32x4 acc = {0.f,0.f,0.f,0.f};
    #pragma unroll
    for (int f=0; f<8; ++f){
      bf16x8 bv = *(const bf16x8*)(wrow + f*32);
      acc = MFMA16(a[f], bv, acc);
    }
    int col = n*16 + lr;
    float bs = ob[col];
    #pragma unroll
    for (int j=0;j<4;++j){
      size_t r = (size_t)(m0 + kg*4 + j);
      xv[n][j] = acc[j] + bs + H[r*128 + col];
    }
  }
  float mu4[4], inv4[4];
  #pragma unroll
  for (int j=0;j<4;++j){
    float s = 0.f, q = 0.f;
    #pragma unroll
    for (int n=0;n<8;++n){ s += xv[n][j]; q += xv[n][j]*xv[n][j]; }
    #pragma unroll
    for (int o=1;o<16;o<<=1){ s += __shfl_xor(s,o); q += __shfl_xor(q,o); }
    float mu  = s * 0.0078125f;
    float var = q * 0.0078125f - mu*mu;
    mu4[j]  = mu;
    inv4[j] = rsqrtf(var + 1e-5f);
  }
  #pragma unroll
  for (int n=0;n<8;++n){
    int col = n*16 + lr;
    float gv = g[col], bv = bb[col];
    #pragma unroll
    for (int j=0;j<4;++j){
      size_t r = (size_t)(m0 + kg*4 + j);
      H[r*128 + col] = (xv[n][j] - mu4[j])*inv4[j]*gv + bv;
    }
  }
}

/* ---------------- two-stage mean over SEQ ---------------- */
__global__ __launch_bounds__(128) void pool1_kernel(
    const float* __restrict__ H, float* __restrict__ PP){
  const int blk = blockIdx.x;            /* (b, tc) : tc fastest */
  const int tc = blk & 15, b = blk >> 4;
  const int d = threadIdx.x;
  float s = 0.f;
  const size_t base = ((size_t)b*SEQ + tc*128);
  for (int t=0;t<128;++t) s += H[(base+t)*128 + d];
  PP[((size_t)b*16 + tc)*128 + d] = s;
}
__global__ __launch_bounds__(128) void pool2_kernel(
    const float* __restrict__ PP, float* __restrict__ P){
  const int b = blockIdx.x, d = threadIdx.x;
  float s = 0.f;
  #pragma unroll
  for (int tc=0;tc<16;++tc) s += PP[((size_t)b*16+tc)*128 + d];
  P[b*128 + d] = s * (1.f/SEQ);
}

/* ---------------- head MLP + final formula ---------------- */
__global__ __launch_bounds__(64) void head_kernel(
    const float* __restrict__ P, const float* __restrict__ o1w,
    const float* __restrict__ o1b, const float* __restrict__ o2w,
    const float* __restrict__ o2b, const float* __restrict__ origins,
    float* __restrict__ out){
  const int b = threadIdx.x;
  if (b >= B_SZ) return;
  float hid[64];
  for (int j=0;j<64;++j){
    float s = o1b[j];
    for (int d=0;d<128;++d) s += P[b*128+d]*o1w[d*64+j];
    hid[j] = fmaxf(s, 0.f);
  }
  float pr[3];
  for (int q=0;q<3;++q){
    float s = o2b[q];
    for (int j=0;j<64;++j) s += hid[j]*o2w[j*3+q];
    pr[q] = 2.f*sigm(s);
  }
  const float* l1 = origins + ((size_t)b*SEQ + (SEQ-1))*16;
  const float* l2 = origins + ((size_t)b*SEQ + (SEQ-2))*16;
  float price=l1[0], ry_n=l1[1], ry_b=l2[1], gy_n=l1[2], gy_b=l2[2], ny_n=l1[3], ny_b=l2[3];
  out[b] = price*pr[0]*ry_n/ry_b*2.f*(pr[1]*sigm(gy_n-gy_b) + pr[2]*sigm(ny_n-ny_b));
}

extern "C" void kernel_launch(void* const* d_in, const int* in_sizes, int n_in,
                              void* d_out, int out_size, void* d_ws, size_t ws_size,
                              hipStream_t stream){
  const float* origins = (const float*)d_in[0];
  const float* x      = (const float*)d_in[1];
  const float* emb_w  = (const float*)d_in[2];
  const float* emb_b  = (const float*)d_in[3];
  const float* in_w   = (const float*)d_in[4];
  const float* in_b   = (const float*)d_in[5];
  const float* xp_w   = (const float*)d_in[6];
  const float* xp_b   = (const float*)d_in[7];
  const float* dt_w   = (const float*)d_in[8];
  const float* dt_b   = (const float*)d_in[9];
  const float* out_w  = (const float*)d_in[10];
  const float* out_b  = (const float*)d_in[11];
  const float* A_log  = (const float*)d_in[12];
  const float* Dp     = (const float*)d_in[13];
  const float* ln_g   = (const float*)d_in[14];
  const float* ln_b   = (const float*)d_in[15];
  const float* o1_w   = (const float*)d_in[16];
  const float* o1_b   = (const float*)d_in[17];
  const float* o2_w   = (const float*)d_in[18];
  const float* o2_b   = (const float*)d_in[19];
  float* outp = (float*)d_out;

  auto al = [](size_t b)->size_t{ return (b + 255) & ~(size_t)255; };
  const size_t wt1_b = al((size_t)NLAYERS*512*128*2);
  const size_t wt2_b = al((size_t)NLAYERS*288*256*2);
  const size_t wt3_b = al((size_t)NLAYERS*128*256*2);
  const size_t po_b  = al((size_t)B_SZ*128*4);
  const size_t pp_b  = al((size_t)B_SZ*16*128*4);
  const size_t fixed = wt1_b + wt2_b + wt3_b + po_b + pp_b;

  /* pick largest batch-chunk CB, then largest NSEG, fitting ws_size */
  int CB = 0, NSEG = 1;
  static const int cbc[7] = {64,32,16,8,4,2,1};
  size_t h_b=0, u_b=0, bc_b=0, sg_b=0;
  for (int i=0;i<7 && !CB;++i){
    int cb = cbc[i];
    size_t hh = al((size_t)cb*SEQ*128*4);
    size_t uu = al((size_t)cb*SEQ*256*2);
    size_t bb = al((size_t)cb*SEQ*32*4);
    size_t base = fixed + hh + 3*uu + bb;
    if (base <= ws_size){
      CB=cb; h_b=hh; u_b=uu; bc_b=bb;
      static const int nsc[4] = {16,8,4,2};
      for (int k=0;k<4;++k){
        size_t sg = al((size_t)cb*nsc[k]*DSTATE*DINNER*4);
        if (base + 2*sg <= ws_size){ NSEG=nsc[k]; sg_b=sg; break; }
      }
    }
  }
  if (!CB) return;

  char* ws = (char*)d_ws;
  size_t off = 0;
  auto take = [&](size_t bytes)->char*{ char* p = ws + off; off += bytes; return p; };
  u16*   WT1 = (u16*)take(wt1_b);
  u16*   WT2 = (u16*)take(wt2_b);
  u16*   WT3 = (u16*)take(wt3_b);
  float* PO  = (float*)take(po_b);
  float* PP  = (float*)take(pp_b);
  float* H   = (float*)take(h_b);
  u16*   U   = (u16*)take(u_b);    /* also holds ys after scan */
  u16*   ZS  = (u16*)take(u_b);
  u16*   DT  = (u16*)take(u_b);
  float* BC  = (float*)take(bc_b);
  float* SGP = NULL; float* SGH = NULL;
  if (NSEG > 1){ SGP = (float*)take(sg_b); SGH = (float*)take(sg_b); }

  prep_kernel<<<3360, 256, 0, stream>>>(in_w, xp_w, dt_w, out_w, WT1, WT2, WT3);

  const int NC = B_SZ / CB;
  const int Mc = CB * SEQ;
  const int L  = SEQ / NSEG;
  for (int ci=0; ci<NC; ++ci){
    const int b0 = ci * CB;
    const size_t R0 = (size_t)b0 * SEQ;
    emb_kernel<<<(Mc*DMODEL)/256, 256, 0, stream>>>(x + R0*16, emb_w, emb_b, H);
    for (int l=0;l<NLAYERS;++l){
      const float* Al = A_log + (size_t)l*DINNER*DSTATE;
      gemm1_kernel<<<Mc/64, 256, 0, stream>>>(H, WT1 + (size_t)l*512*128,
                                              in_b + l*512, U, ZS);
      gemm2_kernel<<<Mc/64, 256, 0, stream>>>(U, WT2 + (size_t)l*288*256,
                                              xp_b + l*32, dt_b + l*256, BC, DT);
      if (NSEG > 1){
        scan_p1<<<CB*4*NSEG, 64, 0, stream>>>(U, DT, BC, Al, SGP, SGH, NSEG, L);
        scan_p2<<<CB*16, 256, 0, stream>>>(SGP, SGH, NSEG);
        scan_p3<<<CB*4*NSEG, 64, 0, stream>>>(U, DT, BC, ZS, Al, Dp + l*DINNER,
                                              SGP, NSEG, L);
      } else {
        scan_kernel<<<CB*4, 64, 0, stream>>>(U, DT, BC, ZS, Al, Dp + l*DINNER);
      }
      gemm3ln_kernel<<<Mc/64, 256, 0, stream>>>(U, WT3 + (size_t)l*128*256,
                                                out_b + l*128, ln_g + l*128,
                                                ln_b + l*128, H);
    }
    pool1_kernel<<<CB*16, 128, 0, stream>>>(H, PP);
    pool2_kernel<<<CB, 128, 0, stream>>>(PP, PO + (size_t)b0*128);
  }
  head_kernel<<<1, 64, 0, stream>>>(PO, o1_w, o1_b, o2_w, o2_b, origins, outp);
}

// Round 4
// 3027.434 us; speedup vs baseline: 3.8147x; 1.1105x over previous
//
#include <hip/hip_runtime.h>
#include <hip/hip_bf16.h>
#include <math.h>

#define B_SZ    64
#define SEQ     2048
#define DMODEL  128
#define DINNER  256
#define DSTATE  16
#define NLAYERS 5

typedef unsigned short u16;
typedef __attribute__((ext_vector_type(8))) short bf16x8;
typedef __attribute__((ext_vector_type(4))) float f32x4;

static __device__ __forceinline__ float bf2f(u16 u){
  union { unsigned u; float f; } a; a.u = ((unsigned)u) << 16; return a.f;
}
static __device__ __forceinline__ u16 f2bf(float f){
  union { float f; unsigned u; } a; a.f = f;
  unsigned r = a.u + 0x7fffu + ((a.u >> 16) & 1u);
  return (u16)(r >> 16);
}
static __device__ __forceinline__ float sigm(float x){ return 1.f/(1.f+__expf(-x)); }
static __device__ __forceinline__ float siluf(float x){ return x/(1.f+__expf(-x)); }

#define MFMA16(a,b,c) __builtin_amdgcn_mfma_f32_16x16x32_bf16((a),(b),(c),0,0,0)

/* ---------------- weight prep: transpose to [N][K] + bf16 ---------------- */
__global__ __launch_bounds__(256) void prep_kernel(
    const float* __restrict__ in_w, const float* __restrict__ xp_w,
    const float* __restrict__ dt_w, const float* __restrict__ out_w,
    u16* __restrict__ WT1, u16* __restrict__ WT2, u16* __restrict__ WT3){
  int idx = blockIdx.x*256 + threadIdx.x;
  const int n1 = NLAYERS*512*128, n2 = NLAYERS*288*256, n3 = NLAYERS*128*256;
  if (idx < n1){
    int l = idx/(512*128), r = idx%(512*128), n = r/128, k = r%128;
    WT1[idx] = f2bf(in_w[((size_t)l*128 + k)*512 + n]);
  } else if (idx < n1+n2){
    int t = idx-n1; int l=t/(288*256), r=t%(288*256), n=r/256, k=r%256;
    float v = (n<32) ? xp_w[((size_t)l*256+k)*32 + n]
                     : dt_w[((size_t)l*256+k)*256 + (n-32)];
    WT2[t] = f2bf(v);
  } else if (idx < n1+n2+n3){
    int t = idx-n1-n2; int l=t/(128*256), r=t%(128*256), n=r/256, k=r%256;
    WT3[t] = f2bf(out_w[((size_t)l*256+k)*128 + n]);
  }
}

/* ------------- embedding: h = x @ emb_w + emb_b (f32 + bf16) ------------- */
__global__ __launch_bounds__(256) void emb_kernel(
    const float* __restrict__ x, const float* __restrict__ ew,
    const float* __restrict__ eb, float* __restrict__ H, u16* __restrict__ Hb){
  int idx = blockIdx.x*256 + threadIdx.x;
  int m = idx >> 7, d = idx & 127;
  float s = eb[d];
  #pragma unroll
  for (int k=0;k<16;++k) s += x[(size_t)m*16+k]*ew[k*128+d];
  H[(size_t)m*128+d] = s;
  Hb[(size_t)m*128+d] = f2bf(s);
}

/* ------- GEMM1 (swapped operands): row-per-lane, packed 8B stores -------- */
__global__ __launch_bounds__(256) void gemm1_kernel(
    const u16* __restrict__ Hb, const u16* __restrict__ WT,
    const float* __restrict__ bias, u16* __restrict__ U, u16* __restrict__ ZS){
  const int lane = threadIdx.x & 63, wave = threadIdx.x >> 6;
  const int m0 = blockIdx.x*64 + wave*16;
  const int lr = lane & 15, kg = lane >> 4;
  bf16x8 hfrag[4];
  const u16* hrow = Hb + (size_t)(m0+lr)*128 + kg*8;
  #pragma unroll
  for (int f=0; f<4; ++f) hfrag[f] = *(const bf16x8*)(hrow + f*32);
  const int m = m0 + lr;
  #pragma unroll 2
  for (int n0=0; n0<512; n0+=16){
    const u16* wrow = WT + (size_t)(n0+lr)*128 + kg*8;
    f32x4 acc = {0.f,0.f,0.f,0.f};
    #pragma unroll
    for (int f=0; f<4; ++f){
      bf16x8 wv = *(const bf16x8*)(wrow + f*32);
      acc = MFMA16(wv, hfrag[f], acc);   /* D: col=lane&15 -> H row, row -> W row */
    }
    const int col0 = n0 + kg*4;
    float4 bs4 = *(const float4*)(bias + col0);
    ushort4 uv;
    uv.x = f2bf(siluf(acc[0]+bs4.x));
    uv.y = f2bf(siluf(acc[1]+bs4.y));
    uv.z = f2bf(siluf(acc[2]+bs4.z));
    uv.w = f2bf(siluf(acc[3]+bs4.w));
    if (col0 < 256) *(ushort4*)(U  + (size_t)m*256 + col0)       = uv;
    else            *(ushort4*)(ZS + (size_t)m*256 + (col0-256)) = uv;
  }
}

/* -- GEMM2 (swapped): BC (bf16) cols 0..31, dt=softplus -> DT bf16 -------- */
__global__ __launch_bounds__(256) void gemm2_kernel(
    const u16* __restrict__ Uin, const u16* __restrict__ WT,
    const float* __restrict__ xpb, const float* __restrict__ dtb,
    u16* __restrict__ BC, u16* __restrict__ DT){
  const int lane = threadIdx.x & 63, wave = threadIdx.x >> 6;
  const int m0 = blockIdx.x*64 + wave*16;
  const int lr = lane & 15, kg = lane >> 4;
  bf16x8 hfrag[8];
  const u16* arow = Uin + (size_t)(m0+lr)*256 + kg*8;
  #pragma unroll
  for (int f=0; f<8; ++f) hfrag[f] = *(const bf16x8*)(arow + f*32);
  const int m = m0 + lr;
  #pragma unroll 2
  for (int n0=0; n0<288; n0+=16){
    const u16* wrow = WT + (size_t)(n0+lr)*256 + kg*8;
    f32x4 acc = {0.f,0.f,0.f,0.f};
    #pragma unroll
    for (int f=0; f<8; ++f){
      bf16x8 wv = *(const bf16x8*)(wrow + f*32);
      acc = MFMA16(wv, hfrag[f], acc);
    }
    const int col0 = n0 + kg*4;
    if (col0 < 32){
      float4 bs4 = *(const float4*)(xpb + col0);
      ushort4 uv;
      uv.x = f2bf(acc[0]+bs4.x); uv.y = f2bf(acc[1]+bs4.y);
      uv.z = f2bf(acc[2]+bs4.z); uv.w = f2bf(acc[3]+bs4.w);
      *(ushort4*)(BC + (size_t)m*32 + col0) = uv;
    } else {
      float4 bs4 = *(const float4*)(dtb + (col0-32));
      float v0=acc[0]+bs4.x, v1=acc[1]+bs4.y, v2=acc[2]+bs4.z, v3=acc[3]+bs4.w;
      ushort4 uv;
      uv.x = f2bf(fmaxf(v0,0.f) + __logf(1.f + __expf(-fabsf(v0))));
      uv.y = f2bf(fmaxf(v1,0.f) + __logf(1.f + __expf(-fabsf(v1))));
      uv.z = f2bf(fmaxf(v2,0.f) + __logf(1.f + __expf(-fabsf(v2))));
      uv.w = f2bf(fmaxf(v3,0.f) + __logf(1.f + __expf(-fabsf(v3))));
      *(ushort4*)(DT + (size_t)m*256 + (col0-32)) = uv;
    }
  }
}

/* depth-4 power tree: pw[i] = r^(i+1), i=0..15 */
static __device__ __forceinline__ void powtree(float r, float* pw){
  float p2=r*r, p3=p2*r, p4=p2*p2;
  float p5=p4*r, p6=p4*p2, p7=p4*p3, p8=p4*p4;
  pw[0]=r;  pw[1]=p2; pw[2]=p3; pw[3]=p4;
  pw[4]=p5; pw[5]=p6; pw[6]=p7; pw[7]=p8;
  pw[8]=p8*r;  pw[9]=p8*p2;  pw[10]=p8*p3;  pw[11]=p8*p4;
  pw[12]=p8*p5; pw[13]=p8*p6; pw[14]=p8*p7; pw[15]=p8*p8;
}

/* ====================== segmented scan (3 passes) ======================== */
/* pass1: local scan from h=0, record end-state (bf16) and sum(dt).        */
__global__ __launch_bounds__(128) void scan_p1(
    const u16* __restrict__ U, const u16* __restrict__ DT,
    const u16* __restrict__ BC, const float* __restrict__ Alog,
    u16* __restrict__ SGH, float* __restrict__ SDT, int nseg, int L){
  const int seg = blockIdx.x % nseg;
  const int rem = blockIdx.x / nseg;
  const int b = rem >> 1;
  const int c = ((rem & 1) << 7) + threadIdx.x;
  float a2[16]; bool geo = true;
  #pragma unroll
  for (int i=0;i<16;++i){
    float A = -__expf(Alog[c*16+i]);
    a2[i] = A * 1.44269504f;
    if (fabsf(A + (float)(i+1)) > 1e-3f) geo = false;
  }
  float h[16];
  #pragma unroll
  for (int i=0;i<16;++i) h[i]=0.f;
  float sdt = 0.f;
  const size_t mbase = (size_t)b*SEQ + (size_t)seg*L;
  if (geo){
    for (int t=0;t<L;++t){
      const size_t m = mbase + t;
      float u  = bf2f(U[m*256+c]);
      float dt = bf2f(DT[m*256+c]);
      bf16x8 b0 = *(const bf16x8*)(BC + m*32);
      float du = dt*u; sdt += dt;
      float r = exp2f(-1.44269504f*dt);
      float pw[16]; powtree(r, pw);
      #pragma unroll
      for (int i=0;i<8;++i)  h[i] = h[i]*pw[i] + du*bf2f((u16)b0[i]);
      bf16x8 b1 = *(const bf16x8*)(BC + m*32 + 8);
      #pragma unroll
      for (int i=8;i<16;++i) h[i] = h[i]*pw[i] + du*bf2f((u16)b1[i-8]);
    }
  } else {
    for (int t=0;t<L;++t){
      const size_t m = mbase + t;
      float u  = bf2f(U[m*256+c]);
      float dt = bf2f(DT[m*256+c]);
      bf16x8 b0 = *(const bf16x8*)(BC + m*32);
      bf16x8 b1 = *(const bf16x8*)(BC + m*32 + 8);
      float du = dt*u; sdt += dt;
      #pragma unroll
      for (int i=0;i<16;++i){
        float Bv = (i<8) ? bf2f((u16)b0[i]) : bf2f((u16)b1[i-8]);
        h[i] = h[i]*exp2f(dt*a2[i]) + du*Bv;
      }
    }
  }
  const size_t kb = ((size_t)b*nseg+seg);
  #pragma unroll
  for (int i=0;i<16;++i) SGH[(kb*16+i)*256 + c] = f2bf(h[i]);
  SDT[kb*256 + c] = sdt;
}

/* pass2: sequential combine; overwrites SGH with h0 entering each segment. */
__global__ __launch_bounds__(256) void scan_p2(
    u16* __restrict__ SGH, const float* __restrict__ SDT,
    const float* __restrict__ Alog, int nseg){
  const int b = blockIdx.x, c = threadIdx.x;
  float a2[16];
  #pragma unroll
  for (int i=0;i<16;++i) a2[i] = -__expf(Alog[c*16+i]) * 1.44269504f;
  float h[16];
  #pragma unroll
  for (int i=0;i<16;++i) h[i]=0.f;
  for (int s=0;s<nseg;++s){
    const size_t kb = ((size_t)b*nseg+s);
    float sdt = SDT[kb*256 + c];
    #pragma unroll
    for (int i=0;i<16;++i){
      size_t k = (kb*16+i)*256 + c;
      float hl = bf2f(SGH[k]);
      SGH[k] = f2bf(h[i]);                 /* h0 entering segment s */
      h[i] = h[i]*exp2f(sdt*a2[i]) + hl;
    }
  }
}

/* pass3: re-scan from h0, emit y*silu(z) in place of U. */
__global__ __launch_bounds__(128) void scan_p3(
    u16* __restrict__ UY, const u16* __restrict__ DT, const u16* __restrict__ BC,
    const u16* __restrict__ ZS, const float* __restrict__ Alog,
    const float* __restrict__ Dp, const u16* __restrict__ SGH, int nseg, int L){
  const int seg = blockIdx.x % nseg;
  const int rem = blockIdx.x / nseg;
  const int b = rem >> 1;
  const int c = ((rem & 1) << 7) + threadIdx.x;
  float a2[16]; bool geo = true;
  #pragma unroll
  for (int i=0;i<16;++i){
    float A = -__expf(Alog[c*16+i]);
    a2[i] = A * 1.44269504f;
    if (fabsf(A + (float)(i+1)) > 1e-3f) geo = false;
  }
  const float Dv = Dp[c];
  const size_t kb = ((size_t)b*nseg+seg);
  float h[16];
  #pragma unroll
  for (int i=0;i<16;++i) h[i] = bf2f(SGH[(kb*16+i)*256 + c]);
  const size_t mbase = (size_t)b*SEQ + (size_t)seg*L;
  if (geo){
    for (int t=0;t<L;++t){
      const size_t m = mbase + t;
      float u  = bf2f(UY[m*256+c]);
      float dt = bf2f(DT[m*256+c]);
      float zs = bf2f(ZS[m*256+c]);
      bf16x8 b0 = *(const bf16x8*)(BC + m*32);
      bf16x8 b1 = *(const bf16x8*)(BC + m*32 + 8);
      float du = dt*u;
      float r = exp2f(-1.44269504f*dt);
      float pw[16]; powtree(r, pw);
      float s0=0.f, s1=0.f;
      #pragma unroll
      for (int i=0;i<8;++i){
        h[i]   = h[i]  *pw[i]   + du*bf2f((u16)b0[i]);
        s0 += h[i]*bf2f((u16)(*(const bf16x8*)(BC + m*32 + 16))[i]);
      }
      #pragma unroll
      for (int i=8;i<16;++i){
        h[i]   = h[i]  *pw[i]   + du*bf2f((u16)b1[i-8]);
        s1 += h[i]*bf2f((u16)(*(const bf16x8*)(BC + m*32 + 24))[i-8]);
      }
      float y = s0 + s1 + Dv*u;
      UY[m*256+c] = f2bf(y*zs);
    }
  } else {
    for (int t=0;t<L;++t){
      const size_t m = mbase + t;
      float u  = bf2f(UY[m*256+c]);
      float dt = bf2f(DT[m*256+c]);
      float zs = bf2f(ZS[m*256+c]);
      bf16x8 b0 = *(const bf16x8*)(BC + m*32);
      bf16x8 b1 = *(const bf16x8*)(BC + m*32 + 8);
      bf16x8 c0 = *(const bf16x8*)(BC + m*32 + 16);
      bf16x8 c1 = *(const bf16x8*)(BC + m*32 + 24);
      float du = dt*u;
      float s0=0.f, s1=0.f;
      #pragma unroll
      for (int i=0;i<8;++i){
        h[i] = h[i]*exp2f(dt*a2[i]) + du*bf2f((u16)b0[i]);
        s0 += h[i]*bf2f((u16)c0[i]);
      }
      #pragma unroll
      for (int i=8;i<16;++i){
        h[i] = h[i]*exp2f(dt*a2[i]) + du*bf2f((u16)b1[i-8]);
        s1 += h[i]*bf2f((u16)c1[i-8]);
      }
      float y = s0 + s1 + Dv*u;
      UY[m*256+c] = f2bf(y*zs);
    }
  }
}

/* ------------- monolithic scan fallback (if scratch doesn't fit) --------- */
__global__ __launch_bounds__(64) void scan_kernel(
    u16* UY, const u16* __restrict__ DT, const u16* __restrict__ BC,
    const u16* __restrict__ ZS, const float* __restrict__ Alog,
    const float* __restrict__ Dp){
  const int b = blockIdx.x >> 2;
  const int c = ((blockIdx.x & 3) << 6) + threadIdx.x;
  float a2[16];
  #pragma unroll
  for (int i=0;i<16;++i) a2[i] = -__expf(Alog[c*16+i]) * 1.44269504f;
  const float Dv = Dp[c];
  float h[16];
  #pragma unroll
  for (int i=0;i<16;++i) h[i]=0.f;
  const size_t mbase = (size_t)b*SEQ;
  for (int t=0;t<SEQ;++t){
    const size_t m = mbase + t;
    float u  = bf2f(UY[m*256+c]);
    float dt = bf2f(DT[m*256+c]);
    float zs = bf2f(ZS[m*256+c]);
    bf16x8 b0 = *(const bf16x8*)(BC + m*32);
    bf16x8 b1 = *(const bf16x8*)(BC + m*32 + 8);
    bf16x8 c0 = *(const bf16x8*)(BC + m*32 + 16);
    bf16x8 c1 = *(const bf16x8*)(BC + m*32 + 24);
    float du = dt*u;
    float s0=0.f, s1=0.f;
    #pragma unroll
    for (int i=0;i<8;++i){
      h[i] = h[i]*exp2f(dt*a2[i]) + du*bf2f((u16)b0[i]);
      s0 += h[i]*bf2f((u16)c0[i]);
    }
    #pragma unroll
    for (int i=8;i<16;++i){
      h[i] = h[i]*exp2f(dt*a2[i]) + du*bf2f((u16)b1[i-8]);
      s1 += h[i]*bf2f((u16)c1[i-8]);
    }
    float y = s0+s1 + Dv*u;
    UY[m*256+c] = f2bf(y*zs);
  }
}

/* --- GEMM3 + residual + LayerNorm fused (swapped operands) -------------- */
__global__ __launch_bounds__(256) void gemm3ln_kernel(
    const u16* __restrict__ YS, const u16* __restrict__ WT,
    const float* __restrict__ ob, const float* __restrict__ g,
    const float* __restrict__ bb, float* __restrict__ H,
    u16* __restrict__ Hb, int writeH){
  const int lane = threadIdx.x & 63, wave = threadIdx.x >> 6;
  const int m0 = blockIdx.x*64 + wave*16;
  const int lr = lane & 15, kg = lane >> 4;
  bf16x8 hfrag[8];
  const u16* arow = YS + (size_t)(m0+lr)*256 + kg*8;
  #pragma unroll
  for (int f=0; f<8; ++f) hfrag[f] = *(const bf16x8*)(arow + f*32);
  const size_t m = (size_t)(m0 + lr);
  float xv[8][4];
  #pragma unroll
  for (int n=0; n<8; ++n){
    const u16* wrow = WT + (size_t)(n*16+lr)*256 + kg*8;
    f32x4 acc = {0.f,0.f,0.f,0.f};
    #pragma unroll
    for (int f=0; f<8; ++f){
      bf16x8 wv = *(const bf16x8*)(wrow + f*32);
      acc = MFMA16(wv, hfrag[f], acc);
    }
    const int col0 = n*16 + kg*4;
    float4 bs4 = *(const float4*)(ob + col0);
    float4 rs4 = *(const float4*)(H + m*128 + col0);
    xv[n][0] = acc[0] + bs4.x + rs4.x;
    xv[n][1] = acc[1] + bs4.y + rs4.y;
    xv[n][2] = acc[2] + bs4.z + rs4.z;
    xv[n][3] = acc[3] + bs4.w + rs4.w;
  }
  /* row stats: lane holds 32 vals of row m; combine the 4 kg-lanes */
  float s = 0.f, q = 0.f;
  #pragma unroll
  for (int n=0;n<8;++n)
    #pragma unroll
    for (int j=0;j<4;++j){ s += xv[n][j]; q += xv[n][j]*xv[n][j]; }
  s += __shfl_xor(s,16); q += __shfl_xor(q,16);
  s += __shfl_xor(s,32); q += __shfl_xor(q,32);
  float mu  = s * 0.0078125f;
  float var = q * 0.0078125f - mu*mu;
  float inv = rsqrtf(var + 1e-5f);
  #pragma unroll
  for (int n=0;n<8;++n){
    const int col0 = n*16 + kg*4;
    float4 g4 = *(const float4*)(g  + col0);
    float4 b4 = *(const float4*)(bb + col0);
    float o0 = (xv[n][0]-mu)*inv*g4.x + b4.x;
    float o1 = (xv[n][1]-mu)*inv*g4.y + b4.y;
    float o2 = (xv[n][2]-mu)*inv*g4.z + b4.z;
    float o3 = (xv[n][3]-mu)*inv*g4.w + b4.w;
    if (writeH){
      float4 ov = {o0,o1,o2,o3};
      *(float4*)(H + m*128 + col0) = ov;
    }
    ushort4 uv; uv.x=f2bf(o0); uv.y=f2bf(o1); uv.z=f2bf(o2); uv.w=f2bf(o3);
    *(ushort4*)(Hb + m*128 + col0) = uv;
  }
}

/* ---------------- two-stage mean over SEQ (reads bf16 Hb) --------------- */
__global__ __launch_bounds__(128) void pool1_kernel(
    const u16* __restrict__ Hb, float* __restrict__ PP){
  const int blk = blockIdx.x;            /* (b, tc) : tc fastest */
  const int tc = blk & 15, b = blk >> 4;
  const int d = threadIdx.x;
  float s = 0.f;
  const size_t base = ((size_t)b*SEQ + tc*128);
  for (int t=0;t<128;++t) s += bf2f(Hb[(base+t)*128 + d]);
  PP[((size_t)b*16 + tc)*128 + d] = s;
}
__global__ __launch_bounds__(128) void pool2_kernel(
    const float* __restrict__ PP, float* __restrict__ P){
  const int b = blockIdx.x, d = threadIdx.x;
  float s = 0.f;
  #pragma unroll
  for (int tc=0;tc<16;++tc) s += PP[((size_t)b*16+tc)*128 + d];
  P[b*128 + d] = s * (1.f/SEQ);
}

/* ------------- head MLP + final formula (block per batch row) ----------- */
__global__ __launch_bounds__(64) void head_kernel(
    const float* __restrict__ P, const float* __restrict__ o1w,
    const float* __restrict__ o1b, const float* __restrict__ o2w,
    const float* __restrict__ o2b, const float* __restrict__ origins,
    float* __restrict__ out){
  const int b = blockIdx.x;
  const int j = threadIdx.x;     /* 64 lanes, one hid each */
  float hv = o1b[j];
  #pragma unroll 4
  for (int d=0; d<128; ++d) hv += P[b*128+d]*o1w[d*64+j];
  hv = fmaxf(hv, 0.f);
  float p0 = hv*o2w[j*3+0], p1 = hv*o2w[j*3+1], p2 = hv*o2w[j*3+2];
  #pragma unroll
  for (int o=1;o<64;o<<=1){
    p0 += __shfl_xor(p0,o); p1 += __shfl_xor(p1,o); p2 += __shfl_xor(p2,o);
  }
  if (j == 0){
    float a = 2.f*sigm(p0 + o2b[0]);
    float bb = 2.f*sigm(p1 + o2b[1]);
    float c = 2.f*sigm(p2 + o2b[2]);
    const float* l1 = origins + ((size_t)b*SEQ + (SEQ-1))*16;
    const float* l2 = origins + ((size_t)b*SEQ + (SEQ-2))*16;
    float price=l1[0], ry_n=l1[1], ry_b=l2[1], gy_n=l1[2], gy_b=l2[2], ny_n=l1[3], ny_b=l2[3];
    out[b] = price*a*ry_n/ry_b*2.f*(bb*sigm(gy_n-gy_b) + c*sigm(ny_n-ny_b));
  }
}

extern "C" void kernel_launch(void* const* d_in, const int* in_sizes, int n_in,
                              void* d_out, int out_size, void* d_ws, size_t ws_size,
                              hipStream_t stream){
  const float* origins = (const float*)d_in[0];
  const float* x      = (const float*)d_in[1];
  const float* emb_w  = (const float*)d_in[2];
  const float* emb_b  = (const float*)d_in[3];
  const float* in_w   = (const float*)d_in[4];
  const float* in_b   = (const float*)d_in[5];
  const float* xp_w   = (const float*)d_in[6];
  const float* xp_b   = (const float*)d_in[7];
  const float* dt_w   = (const float*)d_in[8];
  const float* dt_b   = (const float*)d_in[9];
  const float* out_w  = (const float*)d_in[10];
  const float* out_b  = (const float*)d_in[11];
  const float* A_log  = (const float*)d_in[12];
  const float* Dp     = (const float*)d_in[13];
  const float* ln_g   = (const float*)d_in[14];
  const float* ln_b   = (const float*)d_in[15];
  const float* o1_w   = (const float*)d_in[16];
  const float* o1_b   = (const float*)d_in[17];
  const float* o2_w   = (const float*)d_in[18];
  const float* o2_b   = (const float*)d_in[19];
  float* outp = (float*)d_out;

  auto al = [](size_t b)->size_t{ return (b + 255) & ~(size_t)255; };
  const size_t wt1_b = al((size_t)NLAYERS*512*128*2);
  const size_t wt2_b = al((size_t)NLAYERS*288*256*2);
  const size_t wt3_b = al((size_t)NLAYERS*128*256*2);
  const size_t po_b  = al((size_t)B_SZ*128*4);
  const size_t pp_b  = al((size_t)B_SZ*16*128*4);
  const size_t fixed = wt1_b + wt2_b + wt3_b + po_b + pp_b;

  /* pick largest batch-chunk CB, then largest NSEG, fitting ws_size */
  int CB = 0, NSEG = 1;
  static const int cbc[7] = {64,32,16,8,4,2,1};
  size_t h_b=0, hb_b=0, u_b=0, bc_b=0, sgh_b=0, sdt_b=0;
  for (int i=0;i<7 && !CB;++i){
    int cb = cbc[i];
    size_t hh  = al((size_t)cb*SEQ*128*4);
    size_t hbb = al((size_t)cb*SEQ*128*2);
    size_t uu  = al((size_t)cb*SEQ*256*2);
    size_t bb  = al((size_t)cb*SEQ*32*2);
    size_t base = fixed + hh + hbb + 3*uu + bb;
    if (base <= ws_size){
      CB=cb; h_b=hh; hb_b=hbb; u_b=uu; bc_b=bb;
      static const int nsc[5] = {32,16,8,4,2};
      for (int k=0;k<5;++k){
        size_t sgh = al((size_t)cb*nsc[k]*DSTATE*DINNER*2);
        size_t sdt = al((size_t)cb*nsc[k]*DINNER*4);
        if (base + sgh + sdt <= ws_size){ NSEG=nsc[k]; sgh_b=sgh; sdt_b=sdt; break; }
      }
    }
  }
  if (!CB) return;

  char* ws = (char*)d_ws;
  size_t off = 0;
  auto take = [&](size_t bytes)->char*{ char* p = ws + off; off += bytes; return p; };
  u16*   WT1 = (u16*)take(wt1_b);
  u16*   WT2 = (u16*)take(wt2_b);
  u16*   WT3 = (u16*)take(wt3_b);
  float* PO  = (float*)take(po_b);
  float* PP  = (float*)take(pp_b);
  float* H   = (float*)take(h_b);
  u16*   Hb  = (u16*)take(hb_b);
  u16*   U   = (u16*)take(u_b);    /* also holds ys after scan */
  u16*   ZS  = (u16*)take(u_b);
  u16*   DT  = (u16*)take(u_b);
  u16*   BC  = (u16*)take(bc_b);
  u16*   SGH = NULL; float* SDT = NULL;
  if (NSEG > 1){ SGH = (u16*)take(sgh_b); SDT = (float*)take(sdt_b); }

  prep_kernel<<<3360, 256, 0, stream>>>(in_w, xp_w, dt_w, out_w, WT1, WT2, WT3);

  const int NC = B_SZ / CB;
  const int Mc = CB * SEQ;
  const int L  = SEQ / NSEG;
  for (int ci=0; ci<NC; ++ci){
    const int b0 = ci * CB;
    const size_t R0 = (size_t)b0 * SEQ;
    emb_kernel<<<(Mc*DMODEL)/256, 256, 0, stream>>>(x + R0*16, emb_w, emb_b, H, Hb);
    for (int l=0;l<NLAYERS;++l){
      const float* Al = A_log + (size_t)l*DINNER*DSTATE;
      gemm1_kernel<<<Mc/64, 256, 0, stream>>>(Hb, WT1 + (size_t)l*512*128,
                                              in_b + l*512, U, ZS);
      gemm2_kernel<<<Mc/64, 256, 0, stream>>>(U, WT2 + (size_t)l*288*256,
                                              xp_b + l*32, dt_b + l*256, BC, DT);
      if (NSEG > 1){
        scan_p1<<<CB*2*NSEG, 128, 0, stream>>>(U, DT, BC, Al, SGH, SDT, NSEG, L);
        scan_p2<<<CB, 256, 0, stream>>>(SGH, SDT, Al, NSEG);
        scan_p3<<<CB*2*NSEG, 128, 0, stream>>>(U, DT, BC, ZS, Al, Dp + l*DINNER,
                                               SGH, NSEG, L);
      } else {
        scan_kernel<<<CB*4, 64, 0, stream>>>(U, DT, BC, ZS, Al, Dp + l*DINNER);
      }
      gemm3ln_kernel<<<Mc/64, 256, 0, stream>>>(U, WT3 + (size_t)l*128*256,
                                                out_b + l*128, ln_g + l*128,
                                                ln_b + l*128, H, Hb,
                                                (l < NLAYERS-1) ? 1 : 0);
    }
    pool1_kernel<<<CB*16, 128, 0, stream>>>(Hb, PP);
    pool2_kernel<<<CB, 128, 0, stream>>>(PP, PO + (size_t)b0*128);
  }
  head_kernel<<<B_SZ, 64, 0, stream>>>(PO, o1_w, o1_b, o2_w, o2_b, origins, outp);
}

// Round 5
// 2490.532 us; speedup vs baseline: 4.6371x; 1.2156x over previous
//
#include <hip/hip_runtime.h>
#include <hip/hip_bf16.h>
#include <math.h>

#define B_SZ    64
#define SEQ     2048
#define DMODEL  128
#define DINNER  256
#define DSTATE  16
#define NLAYERS 5

typedef unsigned short u16;
typedef __attribute__((ext_vector_type(8))) short bf16x8;
typedef __attribute__((ext_vector_type(4))) float f32x4;

static __device__ __forceinline__ float bf2f(u16 u){
  union { unsigned u; float f; } a; a.u = ((unsigned)u) << 16; return a.f;
}
static __device__ __forceinline__ u16 f2bf(float f){
  union { float f; unsigned u; } a; a.f = f;
  unsigned r = a.u + 0x7fffu + ((a.u >> 16) & 1u);
  return (u16)(r >> 16);
}
static __device__ __forceinline__ float sigm(float x){ return 1.f/(1.f+__expf(-x)); }
static __device__ __forceinline__ float siluf(float x){ return x/(1.f+__expf(-x)); }

#define MFMA16(a,b,c) __builtin_amdgcn_mfma_f32_16x16x32_bf16((a),(b),(c),0,0,0)

/* ---------------- weight prep: transpose to [N][K] + bf16 ---------------- */
__global__ __launch_bounds__(256) void prep_kernel(
    const float* __restrict__ in_w, const float* __restrict__ xp_w,
    const float* __restrict__ dt_w, const float* __restrict__ out_w,
    u16* __restrict__ WT1, u16* __restrict__ WT2, u16* __restrict__ WT3){
  int idx = blockIdx.x*256 + threadIdx.x;
  const int n1 = NLAYERS*512*128, n2 = NLAYERS*288*256, n3 = NLAYERS*128*256;
  if (idx < n1){
    int l = idx/(512*128), r = idx%(512*128), n = r/128, k = r%128;
    WT1[idx] = f2bf(in_w[((size_t)l*128 + k)*512 + n]);
  } else if (idx < n1+n2){
    int t = idx-n1; int l=t/(288*256), r=t%(288*256), n=r/256, k=r%256;
    float v = (n<32) ? xp_w[((size_t)l*256+k)*32 + n]
                     : dt_w[((size_t)l*256+k)*256 + (n-32)];
    WT2[t] = f2bf(v);
  } else if (idx < n1+n2+n3){
    int t = idx-n1-n2; int l=t/(128*256), r=t%(128*256), n=r/256, k=r%256;
    WT3[t] = f2bf(out_w[((size_t)l*256+k)*128 + n]);
  }
}

/* ------------- embedding: h = x @ emb_w + emb_b (f32 + bf16) ------------- */
__global__ __launch_bounds__(256) void emb_kernel(
    const float* __restrict__ x, const float* __restrict__ ew,
    const float* __restrict__ eb, float* __restrict__ H, u16* __restrict__ Hb){
  int idx = blockIdx.x*256 + threadIdx.x;
  int m = idx >> 7, d = idx & 127;
  float s = eb[d];
  #pragma unroll
  for (int k=0;k<16;++k) s += x[(size_t)m*16+k]*ew[k*128+d];
  H[(size_t)m*128+d] = s;
  Hb[(size_t)m*128+d] = f2bf(s);
}

/* ------- GEMM1: R=4 row-groups/wave (64 rows), swapped operands ---------- */
__global__ __launch_bounds__(256) void gemm1_kernel(
    const u16* __restrict__ Hb, const u16* __restrict__ WT,
    const float* __restrict__ bias, u16* __restrict__ U, u16* __restrict__ ZS){
  const int lane = threadIdx.x & 63, wave = threadIdx.x >> 6;
  const int m0 = blockIdx.x*256 + wave*64;
  const int lr = lane & 15, kg = lane >> 4;
  bf16x8 hfrag[4][4];
  const u16* hrow = Hb + (size_t)(m0+lr)*128 + kg*8;
  #pragma unroll
  for (int g=0; g<4; ++g)
    #pragma unroll
    for (int f=0; f<4; ++f)
      hfrag[g][f] = *(const bf16x8*)(hrow + g*16*128 + f*32);
  #pragma unroll 2
  for (int n0=0; n0<512; n0+=16){
    const u16* wrow = WT + (size_t)(n0+lr)*128 + kg*8;
    bf16x8 wv[4];
    #pragma unroll
    for (int f=0; f<4; ++f) wv[f] = *(const bf16x8*)(wrow + f*32);
    f32x4 acc[4];
    #pragma unroll
    for (int g=0; g<4; ++g){
      acc[g] = (f32x4){0.f,0.f,0.f,0.f};
      #pragma unroll
      for (int f=0; f<4; ++f) acc[g] = MFMA16(wv[f], hfrag[g][f], acc[g]);
    }
    const int col0 = n0 + kg*4;
    float4 bs4 = *(const float4*)(bias + col0);
    #pragma unroll
    for (int g=0; g<4; ++g){
      const int m = m0 + g*16 + lr;
      ushort4 uv;
      uv.x = f2bf(siluf(acc[g][0]+bs4.x));
      uv.y = f2bf(siluf(acc[g][1]+bs4.y));
      uv.z = f2bf(siluf(acc[g][2]+bs4.z));
      uv.w = f2bf(siluf(acc[g][3]+bs4.w));
      if (col0 < 256) *(ushort4*)(U  + (size_t)m*256 + col0)       = uv;
      else            *(ushort4*)(ZS + (size_t)m*256 + (col0-256)) = uv;
    }
  }
}

/* -- GEMM2: R=2 row-groups/wave (32 rows); BC bf16; DT softplus bf16 ------ */
__global__ __launch_bounds__(256) void gemm2_kernel(
    const u16* __restrict__ Uin, const u16* __restrict__ WT,
    const float* __restrict__ xpb, const float* __restrict__ dtb,
    u16* __restrict__ BC, u16* __restrict__ DT){
  const int lane = threadIdx.x & 63, wave = threadIdx.x >> 6;
  const int m0 = blockIdx.x*128 + wave*32;
  const int lr = lane & 15, kg = lane >> 4;
  bf16x8 hfrag[2][8];
  const u16* arow = Uin + (size_t)(m0+lr)*256 + kg*8;
  #pragma unroll
  for (int g=0; g<2; ++g)
    #pragma unroll
    for (int f=0; f<8; ++f)
      hfrag[g][f] = *(const bf16x8*)(arow + g*16*256 + f*32);
  #pragma unroll 2
  for (int n0=0; n0<288; n0+=16){
    const u16* wrow = WT + (size_t)(n0+lr)*256 + kg*8;
    bf16x8 wv[8];
    #pragma unroll
    for (int f=0; f<8; ++f) wv[f] = *(const bf16x8*)(wrow + f*32);
    f32x4 acc[2];
    #pragma unroll
    for (int g=0; g<2; ++g){
      acc[g] = (f32x4){0.f,0.f,0.f,0.f};
      #pragma unroll
      for (int f=0; f<8; ++f) acc[g] = MFMA16(wv[f], hfrag[g][f], acc[g]);
    }
    const int col0 = n0 + kg*4;
    if (col0 < 32){
      float4 bs4 = *(const float4*)(xpb + col0);
      #pragma unroll
      for (int g=0; g<2; ++g){
        const int m = m0 + g*16 + lr;
        ushort4 uv;
        uv.x = f2bf(acc[g][0]+bs4.x); uv.y = f2bf(acc[g][1]+bs4.y);
        uv.z = f2bf(acc[g][2]+bs4.z); uv.w = f2bf(acc[g][3]+bs4.w);
        *(ushort4*)(BC + (size_t)m*32 + col0) = uv;
      }
    } else {
      float4 bs4 = *(const float4*)(dtb + (col0-32));
      #pragma unroll
      for (int g=0; g<2; ++g){
        const int m = m0 + g*16 + lr;
        float v0=acc[g][0]+bs4.x, v1=acc[g][1]+bs4.y;
        float v2=acc[g][2]+bs4.z, v3=acc[g][3]+bs4.w;
        ushort4 uv;
        uv.x = f2bf(fmaxf(v0,0.f) + __logf(1.f + __expf(-fabsf(v0))));
        uv.y = f2bf(fmaxf(v1,0.f) + __logf(1.f + __expf(-fabsf(v1))));
        uv.z = f2bf(fmaxf(v2,0.f) + __logf(1.f + __expf(-fabsf(v2))));
        uv.w = f2bf(fmaxf(v3,0.f) + __logf(1.f + __expf(-fabsf(v3))));
        *(ushort4*)(DT + (size_t)m*256 + (col0-32)) = uv;
      }
    }
  }
}

/* depth-4 power tree: pw[i] = r^(i+1), i=0..15 */
static __device__ __forceinline__ void powtree(float r, float* pw){
  float p2=r*r, p3=p2*r, p4=p2*p2;
  float p5=p4*r, p6=p4*p2, p7=p4*p3, p8=p4*p4;
  pw[0]=r;  pw[1]=p2; pw[2]=p3; pw[3]=p4;
  pw[4]=p5; pw[5]=p6; pw[6]=p7; pw[7]=p8;
  pw[8]=p8*r;  pw[9]=p8*p2;  pw[10]=p8*p3;  pw[11]=p8*p4;
  pw[12]=p8*p5; pw[13]=p8*p6; pw[14]=p8*p7; pw[15]=p8*p8;
}

/* ====================== segmented scan (3 passes) ======================== */
/* block = (b, seg), 256 threads = channel c */
__global__ __launch_bounds__(256) void scan_p1(
    const u16* __restrict__ U, const u16* __restrict__ DT,
    const u16* __restrict__ BC, const float* __restrict__ Alog,
    u16* __restrict__ SGH, float* __restrict__ SDT, int nseg, int L){
  const int seg = blockIdx.x % nseg;
  const int b   = blockIdx.x / nseg;
  const int c   = threadIdx.x;
  float a2[16]; bool geo = true;
  #pragma unroll
  for (int i=0;i<16;++i){
    float A = -__expf(Alog[c*16+i]);
    a2[i] = A * 1.44269504f;
    if (fabsf(A + (float)(i+1)) > 1e-3f) geo = false;
  }
  float h[16];
  #pragma unroll
  for (int i=0;i<16;++i) h[i]=0.f;
  float sdt = 0.f;
  const size_t mbase = (size_t)b*SEQ + (size_t)seg*L;
  if (geo){
    for (int t=0;t<L;++t){
      const size_t m = mbase + t;
      float u  = bf2f(U[m*256+c]);
      float dt = bf2f(DT[m*256+c]);
      bf16x8 b0 = *(const bf16x8*)(BC + m*32);
      bf16x8 b1 = *(const bf16x8*)(BC + m*32 + 8);
      float du = dt*u; sdt += dt;
      float r = exp2f(-1.44269504f*dt);
      float pw[16]; powtree(r, pw);
      #pragma unroll
      for (int i=0;i<8;++i)  h[i]   = h[i]  *pw[i]   + du*bf2f((u16)b0[i]);
      #pragma unroll
      for (int i=8;i<16;++i) h[i]   = h[i]  *pw[i]   + du*bf2f((u16)b1[i-8]);
    }
  } else {
    for (int t=0;t<L;++t){
      const size_t m = mbase + t;
      float u  = bf2f(U[m*256+c]);
      float dt = bf2f(DT[m*256+c]);
      bf16x8 b0 = *(const bf16x8*)(BC + m*32);
      bf16x8 b1 = *(const bf16x8*)(BC + m*32 + 8);
      float du = dt*u; sdt += dt;
      #pragma unroll
      for (int i=0;i<16;++i){
        float Bv = (i<8) ? bf2f((u16)b0[i]) : bf2f((u16)b1[i-8]);
        h[i] = h[i]*exp2f(dt*a2[i]) + du*Bv;
      }
    }
  }
  const size_t kb = ((size_t)b*nseg+seg);
  #pragma unroll
  for (int i=0;i<16;++i) SGH[(kb*16+i)*256 + c] = f2bf(h[i]);
  SDT[kb*256 + c] = sdt;
}

/* pass2: block = (b, state i), 256 threads = c; chain over segments. */
__global__ __launch_bounds__(256) void scan_p2(
    u16* __restrict__ SGH, const float* __restrict__ SDT,
    const float* __restrict__ Alog, int nseg){
  const int i = blockIdx.x & 15, b = blockIdx.x >> 4, c = threadIdx.x;
  const float a2 = -__expf(Alog[c*16+i]) * 1.44269504f;
  float h = 0.f;
  for (int s=0;s<nseg;++s){
    const size_t kb = ((size_t)b*nseg+s);
    float sdt = SDT[kb*256 + c];
    size_t k = (kb*16+i)*256 + c;
    float hl = bf2f(SGH[k]);
    SGH[k] = f2bf(h);                 /* h0 entering segment s */
    h = h*exp2f(sdt*a2) + hl;
  }
}

/* pass3: re-scan from h0, emit y*silu(z) in place of U. */
__global__ __launch_bounds__(256) void scan_p3(
    u16* __restrict__ UY, const u16* __restrict__ DT, const u16* __restrict__ BC,
    const u16* __restrict__ ZS, const float* __restrict__ Alog,
    const float* __restrict__ Dp, const u16* __restrict__ SGH, int nseg, int L){
  const int seg = blockIdx.x % nseg;
  const int b   = blockIdx.x / nseg;
  const int c   = threadIdx.x;
  float a2[16]; bool geo = true;
  #pragma unroll
  for (int i=0;i<16;++i){
    float A = -__expf(Alog[c*16+i]);
    a2[i] = A * 1.44269504f;
    if (fabsf(A + (float)(i+1)) > 1e-3f) geo = false;
  }
  const float Dv = Dp[c];
  const size_t kb = ((size_t)b*nseg+seg);
  float h[16];
  #pragma unroll
  for (int i=0;i<16;++i) h[i] = bf2f(SGH[(kb*16+i)*256 + c]);
  const size_t mbase = (size_t)b*SEQ + (size_t)seg*L;
  if (geo){
    for (int t=0;t<L;++t){
      const size_t m = mbase + t;
      float u  = bf2f(UY[m*256+c]);
      float dt = bf2f(DT[m*256+c]);
      float zs = bf2f(ZS[m*256+c]);
      bf16x8 b0 = *(const bf16x8*)(BC + m*32);
      bf16x8 b1 = *(const bf16x8*)(BC + m*32 + 8);
      bf16x8 c0 = *(const bf16x8*)(BC + m*32 + 16);
      bf16x8 c1 = *(const bf16x8*)(BC + m*32 + 24);
      float du = dt*u;
      float r = exp2f(-1.44269504f*dt);
      float pw[16]; powtree(r, pw);
      float s0=0.f, s1=0.f;
      #pragma unroll
      for (int i=0;i<8;++i){
        h[i] = h[i]*pw[i] + du*bf2f((u16)b0[i]);
        s0 += h[i]*bf2f((u16)c0[i]);
      }
      #pragma unroll
      for (int i=8;i<16;++i){
        h[i] = h[i]*pw[i] + du*bf2f((u16)b1[i-8]);
        s1 += h[i]*bf2f((u16)c1[i-8]);
      }
      float y = s0 + s1 + Dv*u;
      UY[m*256+c] = f2bf(y*zs);
    }
  } else {
    for (int t=0;t<L;++t){
      const size_t m = mbase + t;
      float u  = bf2f(UY[m*256+c]);
      float dt = bf2f(DT[m*256+c]);
      float zs = bf2f(ZS[m*256+c]);
      bf16x8 b0 = *(const bf16x8*)(BC + m*32);
      bf16x8 b1 = *(const bf16x8*)(BC + m*32 + 8);
      bf16x8 c0 = *(const bf16x8*)(BC + m*32 + 16);
      bf16x8 c1 = *(const bf16x8*)(BC + m*32 + 24);
      float du = dt*u;
      float s0=0.f, s1=0.f;
      #pragma unroll
      for (int i=0;i<8;++i){
        h[i] = h[i]*exp2f(dt*a2[i]) + du*bf2f((u16)b0[i]);
        s0 += h[i]*bf2f((u16)c0[i]);
      }
      #pragma unroll
      for (int i=8;i<16;++i){
        h[i] = h[i]*exp2f(dt*a2[i]) + du*bf2f((u16)b1[i-8]);
        s1 += h[i]*bf2f((u16)c1[i-8]);
      }
      float y = s0 + s1 + Dv*u;
      UY[m*256+c] = f2bf(y*zs);
    }
  }
}

/* ------------- monolithic scan fallback (if scratch doesn't fit) --------- */
__global__ __launch_bounds__(64) void scan_kernel(
    u16* UY, const u16* __restrict__ DT, const u16* __restrict__ BC,
    const u16* __restrict__ ZS, const float* __restrict__ Alog,
    const float* __restrict__ Dp){
  const int b = blockIdx.x >> 2;
  const int c = ((blockIdx.x & 3) << 6) + threadIdx.x;
  float a2[16];
  #pragma unroll
  for (int i=0;i<16;++i) a2[i] = -__expf(Alog[c*16+i]) * 1.44269504f;
  const float Dv = Dp[c];
  float h[16];
  #pragma unroll
  for (int i=0;i<16;++i) h[i]=0.f;
  const size_t mbase = (size_t)b*SEQ;
  for (int t=0;t<SEQ;++t){
    const size_t m = mbase + t;
    float u  = bf2f(UY[m*256+c]);
    float dt = bf2f(DT[m*256+c]);
    float zs = bf2f(ZS[m*256+c]);
    bf16x8 b0 = *(const bf16x8*)(BC + m*32);
    bf16x8 b1 = *(const bf16x8*)(BC + m*32 + 8);
    bf16x8 c0 = *(const bf16x8*)(BC + m*32 + 16);
    bf16x8 c1 = *(const bf16x8*)(BC + m*32 + 24);
    float du = dt*u;
    float s0=0.f, s1=0.f;
    #pragma unroll
    for (int i=0;i<8;++i){
      h[i] = h[i]*exp2f(dt*a2[i]) + du*bf2f((u16)b0[i]);
      s0 += h[i]*bf2f((u16)c0[i]);
    }
    #pragma unroll
    for (int i=8;i<16;++i){
      h[i] = h[i]*exp2f(dt*a2[i]) + du*bf2f((u16)b1[i-8]);
      s1 += h[i]*bf2f((u16)c1[i-8]);
    }
    float y = s0+s1 + Dv*u;
    UY[m*256+c] = f2bf(y*zs);
  }
}

/* --- GEMM3 + residual + LayerNorm fused, R=2 row-groups/wave ------------ */
__global__ __launch_bounds__(256) void gemm3ln_kernel(
    const u16* __restrict__ YS, const u16* __restrict__ WT,
    const float* __restrict__ ob, const float* __restrict__ g,
    const float* __restrict__ bb, float* __restrict__ H,
    u16* __restrict__ Hb, int writeH){
  const int lane = threadIdx.x & 63, wave = threadIdx.x >> 6;
  const int m0 = blockIdx.x*128 + wave*32;
  const int lr = lane & 15, kg = lane >> 4;
  bf16x8 hfrag[2][8];
  const u16* arow = YS + (size_t)(m0+lr)*256 + kg*8;
  #pragma unroll
  for (int gg=0; gg<2; ++gg)
    #pragma unroll
    for (int f=0; f<8; ++f)
      hfrag[gg][f] = *(const bf16x8*)(arow + gg*16*256 + f*32);
  float xv[2][8][4];
  #pragma unroll
  for (int n=0; n<8; ++n){
    const u16* wrow = WT + (size_t)(n*16+lr)*256 + kg*8;
    bf16x8 wv[8];
    #pragma unroll
    for (int f=0; f<8; ++f) wv[f] = *(const bf16x8*)(wrow + f*32);
    const int col0 = n*16 + kg*4;
    float4 bs4 = *(const float4*)(ob + col0);
    #pragma unroll
    for (int gg=0; gg<2; ++gg){
      f32x4 acc = {0.f,0.f,0.f,0.f};
      #pragma unroll
      for (int f=0; f<8; ++f) acc = MFMA16(wv[f], hfrag[gg][f], acc);
      const size_t m = (size_t)(m0 + gg*16 + lr);
      float4 rs4 = *(const float4*)(H + m*128 + col0);
      xv[gg][n][0] = acc[0] + bs4.x + rs4.x;
      xv[gg][n][1] = acc[1] + bs4.y + rs4.y;
      xv[gg][n][2] = acc[2] + bs4.z + rs4.z;
      xv[gg][n][3] = acc[3] + bs4.w + rs4.w;
    }
  }
  #pragma unroll
  for (int gg=0; gg<2; ++gg){
    float s = 0.f, q = 0.f;
    #pragma unroll
    for (int n=0;n<8;++n)
      #pragma unroll
      for (int j=0;j<4;++j){ s += xv[gg][n][j]; q += xv[gg][n][j]*xv[gg][n][j]; }
    s += __shfl_xor(s,16); q += __shfl_xor(q,16);
    s += __shfl_xor(s,32); q += __shfl_xor(q,32);
    float mu  = s * 0.0078125f;
    float var = q * 0.0078125f - mu*mu;
    float inv = rsqrtf(var + 1e-5f);
    const size_t m = (size_t)(m0 + gg*16 + lr);
    #pragma unroll
    for (int n=0;n<8;++n){
      const int col0 = n*16 + kg*4;
      float4 g4 = *(const float4*)(g  + col0);
      float4 b4 = *(const float4*)(bb + col0);
      float o0 = (xv[gg][n][0]-mu)*inv*g4.x + b4.x;
      float o1 = (xv[gg][n][1]-mu)*inv*g4.y + b4.y;
      float o2 = (xv[gg][n][2]-mu)*inv*g4.z + b4.z;
      float o3 = (xv[gg][n][3]-mu)*inv*g4.w + b4.w;
      if (writeH){
        float4 ov = {o0,o1,o2,o3};
        *(float4*)(H + m*128 + col0) = ov;
      }
      ushort4 uv; uv.x=f2bf(o0); uv.y=f2bf(o1); uv.z=f2bf(o2); uv.w=f2bf(o3);
      *(ushort4*)(Hb + m*128 + col0) = uv;
    }
  }
}

/* ---------------- two-stage mean over SEQ (reads bf16 Hb) --------------- */
__global__ __launch_bounds__(128) void pool1_kernel(
    const u16* __restrict__ Hb, float* __restrict__ PP){
  const int blk = blockIdx.x;            /* (b, tc) : tc fastest */
  const int tc = blk & 15, b = blk >> 4;
  const int d = threadIdx.x;
  float s = 0.f;
  const size_t base = ((size_t)b*SEQ + tc*128);
  for (int t=0;t<128;++t) s += bf2f(Hb[(base+t)*128 + d]);
  PP[((size_t)b*16 + tc)*128 + d] = s;
}
__global__ __launch_bounds__(128) void pool2_kernel(
    const float* __restrict__ PP, float* __restrict__ P){
  const int b = blockIdx.x, d = threadIdx.x;
  float s = 0.f;
  #pragma unroll
  for (int tc=0;tc<16;++tc) s += PP[((size_t)b*16+tc)*128 + d];
  P[b*128 + d] = s * (1.f/SEQ);
}

/* ------------- head MLP + final formula (block per batch row) ----------- */
__global__ __launch_bounds__(64) void head_kernel(
    const float* __restrict__ P, const float* __restrict__ o1w,
    const float* __restrict__ o1b, const float* __restrict__ o2w,
    const float* __restrict__ o2b, const float* __restrict__ origins,
    float* __restrict__ out){
  const int b = blockIdx.x;
  const int j = threadIdx.x;     /* 64 lanes, one hid each */
  float hv = o1b[j];
  #pragma unroll 4
  for (int d=0; d<128; ++d) hv += P[b*128+d]*o1w[d*64+j];
  hv = fmaxf(hv, 0.f);
  float p0 = hv*o2w[j*3+0], p1 = hv*o2w[j*3+1], p2 = hv*o2w[j*3+2];
  #pragma unroll
  for (int o=1;o<64;o<<=1){
    p0 += __shfl_xor(p0,o); p1 += __shfl_xor(p1,o); p2 += __shfl_xor(p2,o);
  }
  if (j == 0){
    float a = 2.f*sigm(p0 + o2b[0]);
    float bb = 2.f*sigm(p1 + o2b[1]);
    float c = 2.f*sigm(p2 + o2b[2]);
    const float* l1 = origins + ((size_t)b*SEQ + (SEQ-1))*16;
    const float* l2 = origins + ((size_t)b*SEQ + (SEQ-2))*16;
    float price=l1[0], ry_n=l1[1], ry_b=l2[1], gy_n=l1[2], gy_b=l2[2], ny_n=l1[3], ny_b=l2[3];
    out[b] = price*a*ry_n/ry_b*2.f*(bb*sigm(gy_n-gy_b) + c*sigm(ny_n-ny_b));
  }
}

extern "C" void kernel_launch(void* const* d_in, const int* in_sizes, int n_in,
                              void* d_out, int out_size, void* d_ws, size_t ws_size,
                              hipStream_t stream){
  const float* origins = (const float*)d_in[0];
  const float* x      = (const float*)d_in[1];
  const float* emb_w  = (const float*)d_in[2];
  const float* emb_b  = (const float*)d_in[3];
  const float* in_w   = (const float*)d_in[4];
  const float* in_b   = (const float*)d_in[5];
  const float* xp_w   = (const float*)d_in[6];
  const float* xp_b   = (const float*)d_in[7];
  const float* dt_w   = (const float*)d_in[8];
  const float* dt_b   = (const float*)d_in[9];
  const float* out_w  = (const float*)d_in[10];
  const float* out_b  = (const float*)d_in[11];
  const float* A_log  = (const float*)d_in[12];
  const float* Dp     = (const float*)d_in[13];
  const float* ln_g   = (const float*)d_in[14];
  const float* ln_b   = (const float*)d_in[15];
  const float* o1_w   = (const float*)d_in[16];
  const float* o1_b   = (const float*)d_in[17];
  const float* o2_w   = (const float*)d_in[18];
  const float* o2_b   = (const float*)d_in[19];
  float* outp = (float*)d_out;

  auto al = [](size_t b)->size_t{ return (b + 255) & ~(size_t)255; };
  const size_t wt1_b = al((size_t)NLAYERS*512*128*2);
  const size_t wt2_b = al((size_t)NLAYERS*288*256*2);
  const size_t wt3_b = al((size_t)NLAYERS*128*256*2);
  const size_t po_b  = al((size_t)B_SZ*128*4);
  const size_t pp_b  = al((size_t)B_SZ*16*128*4);
  const size_t fixed = wt1_b + wt2_b + wt3_b + po_b + pp_b;

  /* pick largest batch-chunk CB, then largest NSEG, fitting ws_size */
  int CB = 0, NSEG = 1;
  static const int cbc[7] = {64,32,16,8,4,2,1};
  size_t h_b=0, hb_b=0, u_b=0, bc_b=0, sgh_b=0, sdt_b=0;
  for (int i=0;i<7 && !CB;++i){
    int cb = cbc[i];
    size_t hh  = al((size_t)cb*SEQ*128*4);
    size_t hbb = al((size_t)cb*SEQ*128*2);
    size_t uu  = al((size_t)cb*SEQ*256*2);
    size_t bb  = al((size_t)cb*SEQ*32*2);
    size_t base = fixed + hh + hbb + 3*uu + bb;
    if (base <= ws_size){
      CB=cb; h_b=hh; hb_b=hbb; u_b=uu; bc_b=bb;
      static const int nsc[6] = {64,32,16,8,4,2};
      for (int k=0;k<6;++k){
        size_t sgh = al((size_t)cb*nsc[k]*DSTATE*DINNER*2);
        size_t sdt = al((size_t)cb*nsc[k]*DINNER*4);
        if (base + sgh + sdt <= ws_size){ NSEG=nsc[k]; sgh_b=sgh; sdt_b=sdt; break; }
      }
    }
  }
  if (!CB) return;

  char* ws = (char*)d_ws;
  size_t off = 0;
  auto take = [&](size_t bytes)->char*{ char* p = ws + off; off += bytes; return p; };
  u16*   WT1 = (u16*)take(wt1_b);
  u16*   WT2 = (u16*)take(wt2_b);
  u16*   WT3 = (u16*)take(wt3_b);
  float* PO  = (float*)take(po_b);
  float* PP  = (float*)take(pp_b);
  float* H   = (float*)take(h_b);
  u16*   Hb  = (u16*)take(hb_b);
  u16*   U   = (u16*)take(u_b);    /* also holds ys after scan */
  u16*   ZS  = (u16*)take(u_b);
  u16*   DT  = (u16*)take(u_b);
  u16*   BC  = (u16*)take(bc_b);
  u16*   SGH = NULL; float* SDT = NULL;
  if (NSEG > 1){ SGH = (u16*)take(sgh_b); SDT = (float*)take(sdt_b); }

  prep_kernel<<<3360, 256, 0, stream>>>(in_w, xp_w, dt_w, out_w, WT1, WT2, WT3);

  const int NC = B_SZ / CB;
  const int Mc = CB * SEQ;
  const int L  = SEQ / NSEG;
  for (int ci=0; ci<NC; ++ci){
    const int b0 = ci * CB;
    const size_t R0 = (size_t)b0 * SEQ;
    emb_kernel<<<(Mc*DMODEL)/256, 256, 0, stream>>>(x + R0*16, emb_w, emb_b, H, Hb);
    for (int l=0;l<NLAYERS;++l){
      const float* Al = A_log + (size_t)l*DINNER*DSTATE;
      gemm1_kernel<<<Mc/256, 256, 0, stream>>>(Hb, WT1 + (size_t)l*512*128,
                                               in_b + l*512, U, ZS);
      gemm2_kernel<<<Mc/128, 256, 0, stream>>>(U, WT2 + (size_t)l*288*256,
                                               xp_b + l*32, dt_b + l*256, BC, DT);
      if (NSEG > 1){
        scan_p1<<<CB*NSEG, 256, 0, stream>>>(U, DT, BC, Al, SGH, SDT, NSEG, L);
        scan_p2<<<CB*16, 256, 0, stream>>>(SGH, SDT, Al, NSEG);
        scan_p3<<<CB*NSEG, 256, 0, stream>>>(U, DT, BC, ZS, Al, Dp + l*DINNER,
                                             SGH, NSEG, L);
      } else {
        scan_kernel<<<CB*4, 64, 0, stream>>>(U, DT, BC, ZS, Al, Dp + l*DINNER);
      }
      gemm3ln_kernel<<<Mc/128, 256, 0, stream>>>(U, WT3 + (size_t)l*128*256,
                                                 out_b + l*128, ln_g + l*128,
                                                 ln_b + l*128, H, Hb,
                                                 (l < NLAYERS-1) ? 1 : 0);
    }
    pool1_kernel<<<CB*16, 128, 0, stream>>>(Hb, PP);
    pool2_kernel<<<CB, 128, 0, stream>>>(PP, PO + (size_t)b0*128);
  }
  head_kernel<<<B_SZ, 64, 0, stream>>>(PO, o1_w, o1_b, o2_w, o2_b, origins, outp);
}

// Round 6
// 1931.985 us; speedup vs baseline: 5.9777x; 1.2891x over previous
//
#include <hip/hip_runtime.h>
#include <hip/hip_bf16.h>
#include <math.h>

#define B_SZ    64
#define SEQ     2048
#define DMODEL  128
#define DINNER  256
#define DSTATE  16
#define NLAYERS 5

typedef unsigned short u16;
typedef __attribute__((ext_vector_type(8))) short bf16x8;
typedef __attribute__((ext_vector_type(4))) float f32x4;

static __device__ __forceinline__ float bf2f(u16 u){
  union { unsigned u; float f; } a; a.u = ((unsigned)u) << 16; return a.f;
}
static __device__ __forceinline__ u16 f2bf(float f){
  union { float f; unsigned u; } a; a.f = f;
  unsigned r = a.u + 0x7fffu + ((a.u >> 16) & 1u);
  return (u16)(r >> 16);
}
static __device__ __forceinline__ float sigm(float x){ return 1.f/(1.f+__expf(-x)); }
static __device__ __forceinline__ float siluf(float x){ return x/(1.f+__expf(-x)); }

#define MFMA16(a,b,c) __builtin_amdgcn_mfma_f32_16x16x32_bf16((a),(b),(c),0,0,0)

/* ---------------- weight prep: transpose to [N][K] + bf16 ---------------- */
__global__ __launch_bounds__(256) void prep_kernel(
    const float* __restrict__ in_w, const float* __restrict__ xp_w,
    const float* __restrict__ dt_w, const float* __restrict__ out_w,
    u16* __restrict__ WT1, u16* __restrict__ WT2, u16* __restrict__ WT3){
  int idx = blockIdx.x*256 + threadIdx.x;
  const int n1 = NLAYERS*512*128, n2 = NLAYERS*288*256, n3 = NLAYERS*128*256;
  if (idx < n1){
    int l = idx/(512*128), r = idx%(512*128), n = r/128, k = r%128;
    WT1[idx] = f2bf(in_w[((size_t)l*128 + k)*512 + n]);
  } else if (idx < n1+n2){
    int t = idx-n1; int l=t/(288*256), r=t%(288*256), n=r/256, k=r%256;
    float v = (n<32) ? xp_w[((size_t)l*256+k)*32 + n]
                     : dt_w[((size_t)l*256+k)*256 + (n-32)];
    WT2[t] = f2bf(v);
  } else if (idx < n1+n2+n3){
    int t = idx-n1-n2; int l=t/(128*256), r=t%(128*256), n=r/256, k=r%256;
    WT3[t] = f2bf(out_w[((size_t)l*256+k)*128 + n]);
  }
}

/* ------------- embedding: h = x @ emb_w + emb_b (bf16 out) --------------- */
__global__ __launch_bounds__(256) void emb_kernel(
    const float* __restrict__ x, const float* __restrict__ ew,
    const float* __restrict__ eb, u16* __restrict__ Hb){
  int idx = blockIdx.x*256 + threadIdx.x;
  int m = idx >> 7, d = idx & 127;
  float s = eb[d];
  #pragma unroll
  for (int k=0;k<16;++k) s += x[(size_t)m*16+k]*ew[k*128+d];
  Hb[(size_t)m*128+d] = f2bf(s);
}

/* -- GEMM1: R=4 rows/wave, N-split halves, weight-prefetch pipeline ------- */
__global__ __launch_bounds__(256) void gemm1_kernel(
    const u16* __restrict__ Hb, const u16* __restrict__ WT,
    const float* __restrict__ bias, u16* __restrict__ U, u16* __restrict__ ZS){
  const int lane = threadIdx.x & 63, wave = threadIdx.x >> 6;
  const int half = blockIdx.x & 1;
  const int m0 = (blockIdx.x >> 1)*256 + wave*64;
  const int lr = lane & 15, kg = lane >> 4;
  bf16x8 hfrag[4][4];
  const u16* hrow = Hb + (size_t)(m0+lr)*128 + kg*8;
  #pragma unroll
  for (int g=0; g<4; ++g)
    #pragma unroll
    for (int f=0; f<4; ++f)
      hfrag[g][f] = *(const bf16x8*)(hrow + g*16*128 + f*32);
  u16* const dst = half ? ZS : U;
  const u16* wrow = WT + (size_t)(half*256+lr)*128 + kg*8;
  bf16x8 wv[4];
  #pragma unroll
  for (int f=0; f<4; ++f) wv[f] = *(const bf16x8*)(wrow + f*32);
  #pragma unroll
  for (int nn=0; nn<16; ++nn){
    bf16x8 wn[4];
    if (nn < 15){
      const u16* wr2 = wrow + (size_t)(nn+1)*16*128;
      #pragma unroll
      for (int f=0; f<4; ++f) wn[f] = *(const bf16x8*)(wr2 + f*32);
    }
    f32x4 acc[4];
    #pragma unroll
    for (int g=0; g<4; ++g){
      acc[g] = (f32x4){0.f,0.f,0.f,0.f};
      #pragma unroll
      for (int f=0; f<4; ++f) acc[g] = MFMA16(wv[f], hfrag[g][f], acc[g]);
    }
    const int ncol = nn*16 + kg*4;            /* 0..255 within this half */
    float4 bs4 = *(const float4*)(bias + half*256 + ncol);
    #pragma unroll
    for (int g=0; g<4; ++g){
      const int m = m0 + g*16 + lr;
      ushort4 uv;
      uv.x = f2bf(siluf(acc[g][0]+bs4.x));
      uv.y = f2bf(siluf(acc[g][1]+bs4.y));
      uv.z = f2bf(siluf(acc[g][2]+bs4.z));
      uv.w = f2bf(siluf(acc[g][3]+bs4.w));
      *(ushort4*)(dst + (size_t)m*256 + ncol) = uv;
    }
    #pragma unroll
    for (int f=0; f<4; ++f) wv[f] = wn[f];
  }
}

/* -- GEMM2: R=2 rows/wave, weight-prefetch; BC bf16; DT softplus bf16 ----- */
__global__ __launch_bounds__(256) void gemm2_kernel(
    const u16* __restrict__ Uin, const u16* __restrict__ WT,
    const float* __restrict__ xpb, const float* __restrict__ dtb,
    u16* __restrict__ BC, u16* __restrict__ DT){
  const int lane = threadIdx.x & 63, wave = threadIdx.x >> 6;
  const int m0 = blockIdx.x*128 + wave*32;
  const int lr = lane & 15, kg = lane >> 4;
  bf16x8 hfrag[2][8];
  const u16* arow = Uin + (size_t)(m0+lr)*256 + kg*8;
  #pragma unroll
  for (int g=0; g<2; ++g)
    #pragma unroll
    for (int f=0; f<8; ++f)
      hfrag[g][f] = *(const bf16x8*)(arow + g*16*256 + f*32);
  const u16* wrow = WT + (size_t)lr*256 + kg*8;
  bf16x8 wv[8];
  #pragma unroll
  for (int f=0; f<8; ++f) wv[f] = *(const bf16x8*)(wrow + f*32);
  #pragma unroll
  for (int nn=0; nn<18; ++nn){
    bf16x8 wn[8];
    if (nn < 17){
      const u16* wr2 = wrow + (size_t)(nn+1)*16*256;
      #pragma unroll
      for (int f=0; f<8; ++f) wn[f] = *(const bf16x8*)(wr2 + f*32);
    }
    f32x4 acc[2];
    #pragma unroll
    for (int g=0; g<2; ++g){
      acc[g] = (f32x4){0.f,0.f,0.f,0.f};
      #pragma unroll
      for (int f=0; f<8; ++f) acc[g] = MFMA16(wv[f], hfrag[g][f], acc[g]);
    }
    const int col0 = nn*16 + kg*4;
    if (col0 < 32){
      float4 bs4 = *(const float4*)(xpb + col0);
      #pragma unroll
      for (int g=0; g<2; ++g){
        const int m = m0 + g*16 + lr;
        ushort4 uv;
        uv.x = f2bf(acc[g][0]+bs4.x); uv.y = f2bf(acc[g][1]+bs4.y);
        uv.z = f2bf(acc[g][2]+bs4.z); uv.w = f2bf(acc[g][3]+bs4.w);
        *(ushort4*)(BC + (size_t)m*32 + col0) = uv;
      }
    } else {
      float4 bs4 = *(const float4*)(dtb + (col0-32));
      #pragma unroll
      for (int g=0; g<2; ++g){
        const int m = m0 + g*16 + lr;
        float v0=acc[g][0]+bs4.x, v1=acc[g][1]+bs4.y;
        float v2=acc[g][2]+bs4.z, v3=acc[g][3]+bs4.w;
        ushort4 uv;
        uv.x = f2bf(fmaxf(v0,0.f) + __logf(1.f + __expf(-fabsf(v0))));
        uv.y = f2bf(fmaxf(v1,0.f) + __logf(1.f + __expf(-fabsf(v1))));
        uv.z = f2bf(fmaxf(v2,0.f) + __logf(1.f + __expf(-fabsf(v2))));
        uv.w = f2bf(fmaxf(v3,0.f) + __logf(1.f + __expf(-fabsf(v3))));
        *(ushort4*)(DT + (size_t)m*256 + (col0-32)) = uv;
      }
    }
    #pragma unroll
    for (int f=0; f<8; ++f) wv[f] = wn[f];
  }
}

/* depth-4 power tree: pw[i] = r^(i+1), i=0..15 */
static __device__ __forceinline__ void powtree(float r, float* pw){
  float p2=r*r, p3=p2*r, p4=p2*p2;
  float p5=p4*r, p6=p4*p2, p7=p4*p3, p8=p4*p4;
  pw[0]=r;  pw[1]=p2; pw[2]=p3; pw[3]=p4;
  pw[4]=p5; pw[5]=p6; pw[6]=p7; pw[7]=p8;
  pw[8]=p8*r;  pw[9]=p8*p2;  pw[10]=p8*p3;  pw[11]=p8*p4;
  pw[12]=p8*p5; pw[13]=p8*p6; pw[14]=p8*p7; pw[15]=p8*p8;
}

/* ====================== segmented scan (3 passes) ======================== */
__global__ __launch_bounds__(256) void scan_p1(
    const u16* __restrict__ U, const u16* __restrict__ DT,
    const u16* __restrict__ BC, const float* __restrict__ Alog,
    u16* __restrict__ SGH, float* __restrict__ SDT, int nseg, int L){
  const int seg = blockIdx.x % nseg;
  const int b   = blockIdx.x / nseg;
  const int c   = threadIdx.x;
  float a2[16]; bool geo = true;
  #pragma unroll
  for (int i=0;i<16;++i){
    float A = -__expf(Alog[c*16+i]);
    a2[i] = A * 1.44269504f;
    if (fabsf(A + (float)(i+1)) > 1e-3f) geo = false;
  }
  float h[16];
  #pragma unroll
  for (int i=0;i<16;++i) h[i]=0.f;
  float sdt = 0.f;
  const size_t mbase = (size_t)b*SEQ + (size_t)seg*L;
  if (geo){
    for (int t=0;t<L;++t){
      const size_t m = mbase + t;
      float u  = bf2f(U[m*256+c]);
      float dt = bf2f(DT[m*256+c]);
      bf16x8 b0 = *(const bf16x8*)(BC + m*32);
      bf16x8 b1 = *(const bf16x8*)(BC + m*32 + 8);
      float du = dt*u; sdt += dt;
      float r = exp2f(-1.44269504f*dt);
      float pw[16]; powtree(r, pw);
      #pragma unroll
      for (int i=0;i<8;++i)  h[i]   = h[i]  *pw[i]   + du*bf2f((u16)b0[i]);
      #pragma unroll
      for (int i=8;i<16;++i) h[i]   = h[i]  *pw[i]   + du*bf2f((u16)b1[i-8]);
    }
  } else {
    for (int t=0;t<L;++t){
      const size_t m = mbase + t;
      float u  = bf2f(U[m*256+c]);
      float dt = bf2f(DT[m*256+c]);
      bf16x8 b0 = *(const bf16x8*)(BC + m*32);
      bf16x8 b1 = *(const bf16x8*)(BC + m*32 + 8);
      float du = dt*u; sdt += dt;
      #pragma unroll
      for (int i=0;i<16;++i){
        float Bv = (i<8) ? bf2f((u16)b0[i]) : bf2f((u16)b1[i-8]);
        h[i] = h[i]*exp2f(dt*a2[i]) + du*Bv;
      }
    }
  }
  const size_t kb = ((size_t)b*nseg+seg);
  #pragma unroll
  for (int i=0;i<16;++i) SGH[(kb*16+i)*256 + c] = f2bf(h[i]);
  SDT[kb*256 + c] = sdt;
}

__global__ __launch_bounds__(256) void scan_p2(
    u16* __restrict__ SGH, const float* __restrict__ SDT,
    const float* __restrict__ Alog, int nseg){
  const int i = blockIdx.x & 15, b = blockIdx.x >> 4, c = threadIdx.x;
  const float a2 = -__expf(Alog[c*16+i]) * 1.44269504f;
  float h = 0.f;
  for (int s=0;s<nseg;++s){
    const size_t kb = ((size_t)b*nseg+s);
    float sdt = SDT[kb*256 + c];
    size_t k = (kb*16+i)*256 + c;
    float hl = bf2f(SGH[k]);
    SGH[k] = f2bf(h);                 /* h0 entering segment s */
    h = h*exp2f(sdt*a2) + hl;
  }
}

__global__ __launch_bounds__(256) void scan_p3(
    u16* __restrict__ UY, const u16* __restrict__ DT, const u16* __restrict__ BC,
    const u16* __restrict__ ZS, const float* __restrict__ Alog,
    const float* __restrict__ Dp, const u16* __restrict__ SGH, int nseg, int L){
  const int seg = blockIdx.x % nseg;
  const int b   = blockIdx.x / nseg;
  const int c   = threadIdx.x;
  float a2[16]; bool geo = true;
  #pragma unroll
  for (int i=0;i<16;++i){
    float A = -__expf(Alog[c*16+i]);
    a2[i] = A * 1.44269504f;
    if (fabsf(A + (float)(i+1)) > 1e-3f) geo = false;
  }
  const float Dv = Dp[c];
  const size_t kb = ((size_t)b*nseg+seg);
  float h[16];
  #pragma unroll
  for (int i=0;i<16;++i) h[i] = bf2f(SGH[(kb*16+i)*256 + c]);
  const size_t mbase = (size_t)b*SEQ + (size_t)seg*L;
  if (geo){
    for (int t=0;t<L;++t){
      const size_t m = mbase + t;
      float u  = bf2f(UY[m*256+c]);
      float dt = bf2f(DT[m*256+c]);
      float zs = bf2f(ZS[m*256+c]);
      bf16x8 b0 = *(const bf16x8*)(BC + m*32);
      bf16x8 b1 = *(const bf16x8*)(BC + m*32 + 8);
      bf16x8 c0 = *(const bf16x8*)(BC + m*32 + 16);
      bf16x8 c1 = *(const bf16x8*)(BC + m*32 + 24);
      float du = dt*u;
      float r = exp2f(-1.44269504f*dt);
      float pw[16]; powtree(r, pw);
      float s0=0.f, s1=0.f;
      #pragma unroll
      for (int i=0;i<8;++i){
        h[i] = h[i]*pw[i] + du*bf2f((u16)b0[i]);
        s0 += h[i]*bf2f((u16)c0[i]);
      }
      #pragma unroll
      for (int i=8;i<16;++i){
        h[i] = h[i]*pw[i] + du*bf2f((u16)b1[i-8]);
        s1 += h[i]*bf2f((u16)c1[i-8]);
      }
      float y = s0 + s1 + Dv*u;
      UY[m*256+c] = f2bf(y*zs);
    }
  } else {
    for (int t=0;t<L;++t){
      const size_t m = mbase + t;
      float u  = bf2f(UY[m*256+c]);
      float dt = bf2f(DT[m*256+c]);
      float zs = bf2f(ZS[m*256+c]);
      bf16x8 b0 = *(const bf16x8*)(BC + m*32);
      bf16x8 b1 = *(const bf16x8*)(BC + m*32 + 8);
      bf16x8 c0 = *(const bf16x8*)(BC + m*32 + 16);
      bf16x8 c1 = *(const bf16x8*)(BC + m*32 + 24);
      float du = dt*u;
      float s0=0.f, s1=0.f;
      #pragma unroll
      for (int i=0;i<8;++i){
        h[i] = h[i]*exp2f(dt*a2[i]) + du*bf2f((u16)b0[i]);
        s0 += h[i]*bf2f((u16)c0[i]);
      }
      #pragma unroll
      for (int i=8;i<16;++i){
        h[i] = h[i]*exp2f(dt*a2[i]) + du*bf2f((u16)b1[i-8]);
        s1 += h[i]*bf2f((u16)c1[i-8]);
      }
      float y = s0 + s1 + Dv*u;
      UY[m*256+c] = f2bf(y*zs);
    }
  }
}

/* ------------- monolithic scan fallback (if scratch doesn't fit) --------- */
__global__ __launch_bounds__(64) void scan_kernel(
    u16* UY, const u16* __restrict__ DT, const u16* __restrict__ BC,
    const u16* __restrict__ ZS, const float* __restrict__ Alog,
    const float* __restrict__ Dp){
  const int b = blockIdx.x >> 2;
  const int c = ((blockIdx.x & 3) << 6) + threadIdx.x;
  float a2[16];
  #pragma unroll
  for (int i=0;i<16;++i) a2[i] = -__expf(Alog[c*16+i]) * 1.44269504f;
  const float Dv = Dp[c];
  float h[16];
  #pragma unroll
  for (int i=0;i<16;++i) h[i]=0.f;
  const size_t mbase = (size_t)b*SEQ;
  for (int t=0;t<SEQ;++t){
    const size_t m = mbase + t;
    float u  = bf2f(UY[m*256+c]);
    float dt = bf2f(DT[m*256+c]);
    float zs = bf2f(ZS[m*256+c]);
    bf16x8 b0 = *(const bf16x8*)(BC + m*32);
    bf16x8 b1 = *(const bf16x8*)(BC + m*32 + 8);
    bf16x8 c0 = *(const bf16x8*)(BC + m*32 + 16);
    bf16x8 c1 = *(const bf16x8*)(BC + m*32 + 24);
    float du = dt*u;
    float s0=0.f, s1=0.f;
    #pragma unroll
    for (int i=0;i<8;++i){
      h[i] = h[i]*exp2f(dt*a2[i]) + du*bf2f((u16)b0[i]);
      s0 += h[i]*bf2f((u16)c0[i]);
    }
    #pragma unroll
    for (int i=8;i<16;++i){
      h[i] = h[i]*exp2f(dt*a2[i]) + du*bf2f((u16)b1[i-8]);
      s1 += h[i]*bf2f((u16)c1[i-8]);
    }
    float y = s0+s1 + Dv*u;
    UY[m*256+c] = f2bf(y*zs);
  }
}

/* --- GEMM3 + bf16 residual + LayerNorm fused, prefetch, packed xv ------- */
__global__ __launch_bounds__(256) void gemm3ln_kernel(
    const u16* __restrict__ YS, const u16* __restrict__ WT,
    const float* __restrict__ ob, const float* __restrict__ g,
    const float* __restrict__ bb, u16* __restrict__ Hb){
  const int lane = threadIdx.x & 63, wave = threadIdx.x >> 6;
  const int m0 = blockIdx.x*128 + wave*32;
  const int lr = lane & 15, kg = lane >> 4;
  bf16x8 hfrag[2][8];
  const u16* arow = YS + (size_t)(m0+lr)*256 + kg*8;
  #pragma unroll
  for (int gg=0; gg<2; ++gg)
    #pragma unroll
    for (int f=0; f<8; ++f)
      hfrag[gg][f] = *(const bf16x8*)(arow + gg*16*256 + f*32);
  const u16* wrow = WT + (size_t)lr*256 + kg*8;
  bf16x8 wv[8];
  #pragma unroll
  for (int f=0; f<8; ++f) wv[f] = *(const bf16x8*)(wrow + f*32);
  ushort4 xvp[2][8];
  float s[2] = {0.f,0.f}, q[2] = {0.f,0.f};
  #pragma unroll
  for (int n=0; n<8; ++n){
    bf16x8 wn[8];
    if (n < 7){
      const u16* wr2 = wrow + (size_t)(n+1)*16*256;
      #pragma unroll
      for (int f=0; f<8; ++f) wn[f] = *(const bf16x8*)(wr2 + f*32);
    }
    const int col0 = n*16 + kg*4;
    float4 bs4 = *(const float4*)(ob + col0);
    #pragma unroll
    for (int gg=0; gg<2; ++gg){
      f32x4 acc = {0.f,0.f,0.f,0.f};
      #pragma unroll
      for (int f=0; f<8; ++f) acc = MFMA16(wv[f], hfrag[gg][f], acc);
      const size_t m = (size_t)(m0 + gg*16 + lr);
      ushort4 rs = *(const ushort4*)(Hb + m*128 + col0);
      float x0 = acc[0] + bs4.x + bf2f(rs.x);
      float x1 = acc[1] + bs4.y + bf2f(rs.y);
      float x2 = acc[2] + bs4.z + bf2f(rs.z);
      float x3 = acc[3] + bs4.w + bf2f(rs.w);
      s[gg] += (x0+x1)+(x2+x3);
      q[gg] += (x0*x0+x1*x1)+(x2*x2+x3*x3);
      ushort4 pv; pv.x=f2bf(x0); pv.y=f2bf(x1); pv.z=f2bf(x2); pv.w=f2bf(x3);
      xvp[gg][n] = pv;
    }
    #pragma unroll
    for (int f=0; f<8; ++f) wv[f] = wn[f];
  }
  #pragma unroll
  for (int gg=0; gg<2; ++gg){
    float ss = s[gg], qq = q[gg];
    ss += __shfl_xor(ss,16); qq += __shfl_xor(qq,16);
    ss += __shfl_xor(ss,32); qq += __shfl_xor(qq,32);
    float mu  = ss * 0.0078125f;
    float var = qq * 0.0078125f - mu*mu;
    float inv = rsqrtf(var + 1e-5f);
    const size_t m = (size_t)(m0 + gg*16 + lr);
    #pragma unroll
    for (int n=0;n<8;++n){
      const int col0 = n*16 + kg*4;
      float4 g4 = *(const float4*)(g  + col0);
      float4 b4 = *(const float4*)(bb + col0);
      ushort4 pv = xvp[gg][n];
      ushort4 uv;
      uv.x = f2bf((bf2f(pv.x)-mu)*inv*g4.x + b4.x);
      uv.y = f2bf((bf2f(pv.y)-mu)*inv*g4.y + b4.y);
      uv.z = f2bf((bf2f(pv.z)-mu)*inv*g4.z + b4.z);
      uv.w = f2bf((bf2f(pv.w)-mu)*inv*g4.w + b4.w);
      *(ushort4*)(Hb + m*128 + col0) = uv;
    }
  }
}

/* ---------------- two-stage mean over SEQ (reads bf16 Hb) --------------- */
__global__ __launch_bounds__(128) void pool1_kernel(
    const u16* __restrict__ Hb, float* __restrict__ PP){
  const int blk = blockIdx.x;            /* (b, tc) : tc fastest */
  const int tc = blk & 15, b = blk >> 4;
  const int d = threadIdx.x;
  float s = 0.f;
  const size_t base = ((size_t)b*SEQ + tc*128);
  for (int t=0;t<128;++t) s += bf2f(Hb[(base+t)*128 + d]);
  PP[((size_t)b*16 + tc)*128 + d] = s;
}
__global__ __launch_bounds__(128) void pool2_kernel(
    const float* __restrict__ PP, float* __restrict__ P){
  const int b = blockIdx.x, d = threadIdx.x;
  float s = 0.f;
  #pragma unroll
  for (int tc=0;tc<16;++tc) s += PP[((size_t)b*16+tc)*128 + d];
  P[b*128 + d] = s * (1.f/SEQ);
}

/* ------------- head MLP + final formula (block per batch row) ----------- */
__global__ __launch_bounds__(64) void head_kernel(
    const float* __restrict__ P, const float* __restrict__ o1w,
    const float* __restrict__ o1b, const float* __restrict__ o2w,
    const float* __restrict__ o2b, const float* __restrict__ origins,
    float* __restrict__ out){
  const int b = blockIdx.x;
  const int j = threadIdx.x;     /* 64 lanes, one hid each */
  float hv = o1b[j];
  #pragma unroll 4
  for (int d=0; d<128; ++d) hv += P[b*128+d]*o1w[d*64+j];
  hv = fmaxf(hv, 0.f);
  float p0 = hv*o2w[j*3+0], p1 = hv*o2w[j*3+1], p2 = hv*o2w[j*3+2];
  #pragma unroll
  for (int o=1;o<64;o<<=1){
    p0 += __shfl_xor(p0,o); p1 += __shfl_xor(p1,o); p2 += __shfl_xor(p2,o);
  }
  if (j == 0){
    float a = 2.f*sigm(p0 + o2b[0]);
    float bb = 2.f*sigm(p1 + o2b[1]);
    float c = 2.f*sigm(p2 + o2b[2]);
    const float* l1 = origins + ((size_t)b*SEQ + (SEQ-1))*16;
    const float* l2 = origins + ((size_t)b*SEQ + (SEQ-2))*16;
    float price=l1[0], ry_n=l1[1], ry_b=l2[1], gy_n=l1[2], gy_b=l2[2], ny_n=l1[3], ny_b=l2[3];
    out[b] = price*a*ry_n/ry_b*2.f*(bb*sigm(gy_n-gy_b) + c*sigm(ny_n-ny_b));
  }
}

extern "C" void kernel_launch(void* const* d_in, const int* in_sizes, int n_in,
                              void* d_out, int out_size, void* d_ws, size_t ws_size,
                              hipStream_t stream){
  const float* origins = (const float*)d_in[0];
  const float* x      = (const float*)d_in[1];
  const float* emb_w  = (const float*)d_in[2];
  const float* emb_b  = (const float*)d_in[3];
  const float* in_w   = (const float*)d_in[4];
  const float* in_b   = (const float*)d_in[5];
  const float* xp_w   = (const float*)d_in[6];
  const float* xp_b   = (const float*)d_in[7];
  const float* dt_w   = (const float*)d_in[8];
  const float* dt_b   = (const float*)d_in[9];
  const float* out_w  = (const float*)d_in[10];
  const float* out_b  = (const float*)d_in[11];
  const float* A_log  = (const float*)d_in[12];
  const float* Dp     = (const float*)d_in[13];
  const float* ln_g   = (const float*)d_in[14];
  const float* ln_b   = (const float*)d_in[15];
  const float* o1_w   = (const float*)d_in[16];
  const float* o1_b   = (const float*)d_in[17];
  const float* o2_w   = (const float*)d_in[18];
  const float* o2_b   = (const float*)d_in[19];
  float* outp = (float*)d_out;

  auto al = [](size_t b)->size_t{ return (b + 255) & ~(size_t)255; };
  const size_t wt1_b = al((size_t)NLAYERS*512*128*2);
  const size_t wt2_b = al((size_t)NLAYERS*288*256*2);
  const size_t wt3_b = al((size_t)NLAYERS*128*256*2);
  const size_t po_b  = al((size_t)B_SZ*128*4);
  const size_t pp_b  = al((size_t)B_SZ*16*128*4);
  const size_t fixed = wt1_b + wt2_b + wt3_b + po_b + pp_b;

  /* pick largest batch-chunk CB, then largest NSEG, fitting ws_size */
  int CB = 0, NSEG = 1;
  static const int cbc[7] = {64,32,16,8,4,2,1};
  size_t hb_b=0, u_b=0, bc_b=0, sgh_b=0, sdt_b=0;
  for (int i=0;i<7 && !CB;++i){
    int cb = cbc[i];
    size_t hbb = al((size_t)cb*SEQ*128*2);
    size_t uu  = al((size_t)cb*SEQ*256*2);
    size_t bb  = al((size_t)cb*SEQ*32*2);
    size_t base = fixed + hbb + 3*uu + bb;
    if (base <= ws_size){
      CB=cb; hb_b=hbb; u_b=uu; bc_b=bb;
      static const int nsc[6] = {64,32,16,8,4,2};
      for (int k=0;k<6;++k){
        size_t sgh = al((size_t)cb*nsc[k]*DSTATE*DINNER*2);
        size_t sdt = al((size_t)cb*nsc[k]*DINNER*4);
        if (base + sgh + sdt <= ws_size){ NSEG=nsc[k]; sgh_b=sgh; sdt_b=sdt; break; }
      }
    }
  }
  if (!CB) return;

  char* ws = (char*)d_ws;
  size_t off = 0;
  auto take = [&](size_t bytes)->char*{ char* p = ws + off; off += bytes; return p; };
  u16*   WT1 = (u16*)take(wt1_b);
  u16*   WT2 = (u16*)take(wt2_b);
  u16*   WT3 = (u16*)take(wt3_b);
  float* PO  = (float*)take(po_b);
  float* PP  = (float*)take(pp_b);
  u16*   Hb  = (u16*)take(hb_b);
  u16*   U   = (u16*)take(u_b);    /* also holds ys after scan */
  u16*   ZS  = (u16*)take(u_b);
  u16*   DT  = (u16*)take(u_b);
  u16*   BC  = (u16*)take(bc_b);
  u16*   SGH = NULL; float* SDT = NULL;
  if (NSEG > 1){ SGH = (u16*)take(sgh_b); SDT = (float*)take(sdt_b); }

  prep_kernel<<<3360, 256, 0, stream>>>(in_w, xp_w, dt_w, out_w, WT1, WT2, WT3);

  const int NC = B_SZ / CB;
  const int Mc = CB * SEQ;
  const int L  = SEQ / NSEG;
  for (int ci=0; ci<NC; ++ci){
    const int b0 = ci * CB;
    const size_t R0 = (size_t)b0 * SEQ;
    emb_kernel<<<(Mc*DMODEL)/256, 256, 0, stream>>>(x + R0*16, emb_w, emb_b, Hb);
    for (int l=0;l<NLAYERS;++l){
      const float* Al = A_log + (size_t)l*DINNER*DSTATE;
      gemm1_kernel<<<(Mc/256)*2, 256, 0, stream>>>(Hb, WT1 + (size_t)l*512*128,
                                                   in_b + l*512, U, ZS);
      gemm2_kernel<<<Mc/128, 256, 0, stream>>>(U, WT2 + (size_t)l*288*256,
                                               xp_b + l*32, dt_b + l*256, BC, DT);
      if (NSEG > 1){
        scan_p1<<<CB*NSEG, 256, 0, stream>>>(U, DT, BC, Al, SGH, SDT, NSEG, L);
        scan_p2<<<CB*16, 256, 0, stream>>>(SGH, SDT, Al, NSEG);
        scan_p3<<<CB*NSEG, 256, 0, stream>>>(U, DT, BC, ZS, Al, Dp + l*DINNER,
                                             SGH, NSEG, L);
      } else {
        scan_kernel<<<CB*4, 64, 0, stream>>>(U, DT, BC, ZS, Al, Dp + l*DINNER);
      }
      gemm3ln_kernel<<<Mc/128, 256, 0, stream>>>(U, WT3 + (size_t)l*128*256,
                                                 out_b + l*128, ln_g + l*128,
                                                 ln_b + l*128, Hb);
    }
    pool1_kernel<<<CB*16, 128, 0, stream>>>(Hb, PP);
    pool2_kernel<<<CB, 128, 0, stream>>>(PP, PO + (size_t)b0*128);
  }
  head_kernel<<<B_SZ, 64, 0, stream>>>(PO, o1_w, o1_b, o2_w, o2_b, origins, outp);
}